// Round 1
// baseline (1466.651 us; speedup 1.0000x reference)
//
#include <hip/hip_runtime.h>
#include <math.h>

#define B_ 4
#define T_ 2048
#define C_ 768
#define H_ 12
#define D_ 64
#define M_ (B_*T_)        // 8192 tokens
#define QKV_N (3*C_)      // 2304

// Static device scratch (load-time allocation; safe for graph capture).
// Layout: q/k/v as [B][H][T][D]; y as [B][T][C] (attention output, pre-projection).
__device__ float g_q[M_*C_];
__device__ float g_k[M_*C_];
__device__ float g_v[M_*C_];
__device__ float g_y[M_*C_];

// ---------------------------------------------------------------------------
// Kernel 1: qkv = x @ W_attn + b_attn, scattered into g_q/g_k/g_v [B][H][T][D]
// 128x128 tile, BK=16, 256 threads, 8x8 micro-tile.
// ---------------------------------------------------------------------------
__global__ __launch_bounds__(256) void k_qkv_gemm(const float* __restrict__ x,
                                                  const float* __restrict__ W,
                                                  const float* __restrict__ bias)
{
    __shared__ float As[16][132];   // [k][m], +4 pad to spread banks
    __shared__ float Bs[16][128];   // [k][n]

    const int tid = threadIdx.x;
    const int ty = tid >> 4;        // 0..15 -> row group of 8
    const int tx = tid & 15;        // 0..15 -> col group of 8
    const int m0 = blockIdx.x * 128;
    const int n0 = blockIdx.y * 128;

    const int ar = tid >> 2;        // 0..63
    const int ac = (tid & 3) * 4;   // 0,4,8,12
    const int br = tid >> 4;        // 0..15
    const int bc = (tid & 15) * 4;  // 0..60

    float acc[8][8];
    #pragma unroll
    for (int i = 0; i < 8; ++i)
        #pragma unroll
        for (int j = 0; j < 8; ++j) acc[i][j] = 0.f;

    for (int k0 = 0; k0 < C_; k0 += 16) {
        float4 a0 = *(const float4*)&x[(size_t)(m0+ar   )*C_ + k0 + ac];
        float4 a1 = *(const float4*)&x[(size_t)(m0+ar+64)*C_ + k0 + ac];
        float4 b0 = *(const float4*)&W[(size_t)(k0+br)*QKV_N + n0 + bc];
        float4 b1 = *(const float4*)&W[(size_t)(k0+br)*QKV_N + n0 + 64 + bc];
        __syncthreads();
        As[ac+0][ar   ] = a0.x; As[ac+1][ar   ] = a0.y; As[ac+2][ar   ] = a0.z; As[ac+3][ar   ] = a0.w;
        As[ac+0][ar+64] = a1.x; As[ac+1][ar+64] = a1.y; As[ac+2][ar+64] = a1.z; As[ac+3][ar+64] = a1.w;
        *(float4*)&Bs[br][bc]      = b0;
        *(float4*)&Bs[br][bc + 64] = b1;
        __syncthreads();
        #pragma unroll
        for (int kk = 0; kk < 16; ++kk) {
            float4 A0 = *(const float4*)&As[kk][ty*8];
            float4 A1 = *(const float4*)&As[kk][ty*8+4];
            float4 B0 = *(const float4*)&Bs[kk][tx*8];
            float4 B1 = *(const float4*)&Bs[kk][tx*8+4];
            float av[8] = {A0.x,A0.y,A0.z,A0.w,A1.x,A1.y,A1.z,A1.w};
            float bv[8] = {B0.x,B0.y,B0.z,B0.w,B1.x,B1.y,B1.z,B1.w};
            #pragma unroll
            for (int i = 0; i < 8; ++i)
                #pragma unroll
                for (int j = 0; j < 8; ++j)
                    acc[i][j] = fmaf(av[i], bv[j], acc[i][j]);
        }
    }

    // Epilogue: tile spans exactly 2 head-blocks of 64 (128 | 768, so `which` is constant).
    const int which = n0 / C_;                       // 0=q 1=k 2=v
    float* outp = (which == 0) ? g_q : (which == 1) ? g_k : g_v;
    const int h0 = (n0 % C_) / D_;
    const int h  = h0 + (tx >> 3);
    const int d0 = (tx & 7) * 8;
    float4 bias0 = *(const float4*)&bias[n0 + tx*8];
    float4 bias1 = *(const float4*)&bias[n0 + tx*8 + 4];
    #pragma unroll
    for (int i = 0; i < 8; ++i) {
        const int m  = m0 + ty*8 + i;
        const int bb = m >> 11;        // / 2048
        const int t  = m & 2047;
        float* rowp = outp + (((size_t)(bb*H_ + h)*T_ + t)*D_ + d0);
        float4 o0, o1;
        o0.x = acc[i][0] + bias0.x; o0.y = acc[i][1] + bias0.y;
        o0.z = acc[i][2] + bias0.z; o0.w = acc[i][3] + bias0.w;
        o1.x = acc[i][4] + bias1.x; o1.y = acc[i][5] + bias1.y;
        o1.z = acc[i][6] + bias1.z; o1.w = acc[i][7] + bias1.w;
        *(float4*)rowp     = o0;
        *(float4*)(rowp+4) = o1;
    }
}

// ---------------------------------------------------------------------------
// Kernel 2: flash-style causal attention with temporal decay.
// One block = (b,h) x 64 q-rows. 256 threads, 16x16 layout, 4x4 micro-tiles.
// Exact reference math: final = e' / (sum(e') + 1e-8*Z), e' = exp(s - m)*exp(-r*(i-j)),
// m/Z = undecayed running max / sum (so the 1e-8 term matches the reference bit-for-bit
// in structure).
// ---------------------------------------------------------------------------
__global__ __launch_bounds__(256) void k_attn(const float* __restrict__ rates)
{
    __shared__ float Qt[64][64];    // [d][i]  (Q transposed)
    __shared__ float Kt[64][64];    // [d][j]  (K transposed)
    __shared__ float Vs[64][68];    // [j][d]  (+4 pad)
    __shared__ float Ps[64][68];    // [i][j]  (+4 pad)
    __shared__ float dtab[T_];      // exp(-rate * delta)

    const int tid = threadIdx.x;
    const int qt  = blockIdx.x;
    const int bh  = blockIdx.y;
    const int h   = bh % H_;
    const float rate = rates[h];
    const int i0  = qt * 64;

    for (int idx = tid; idx < T_; idx += 256)
        dtab[idx] = __expf(-rate * (float)idx);

    const float* qb = g_q + (size_t)bh * T_ * D_;
    const float* kb = g_k + (size_t)bh * T_ * D_;
    const float* vb = g_v + (size_t)bh * T_ * D_;

    // load Q tile transposed
    {
        const int r  = tid & 63;
        const int dq = (tid >> 6) * 16;
        const float4* src = (const float4*)&qb[(size_t)(i0 + r)*D_ + dq];
        #pragma unroll
        for (int c = 0; c < 4; ++c) {
            float4 t4 = src[c];
            Qt[dq + c*4 + 0][r] = t4.x;
            Qt[dq + c*4 + 1][r] = t4.y;
            Qt[dq + c*4 + 2][r] = t4.z;
            Qt[dq + c*4 + 3][r] = t4.w;
        }
    }

    const int ty = tid >> 4;
    const int tx = tid & 15;

    float m_run[4], Zr[4], den[4];
    float acc[4][4];
    #pragma unroll
    for (int i = 0; i < 4; ++i) {
        m_run[i] = -INFINITY; Zr[i] = 0.f; den[i] = 0.f;
        #pragma unroll
        for (int j = 0; j < 4; ++j) acc[i][j] = 0.f;
    }

    for (int j0 = 0; j0 <= i0; j0 += 64) {
        // prefetch K/V tile to regs
        const int r   = tid & 63;
        const int dq  = (tid >> 6) * 16;
        const int jr  = tid >> 2;
        const int seg = (tid & 3) * 16;
        float4 kt4[4], vv4[4];
        const float4* ksrc = (const float4*)&kb[(size_t)(j0 + r )*D_ + dq];
        const float4* vsrc = (const float4*)&vb[(size_t)(j0 + jr)*D_ + seg];
        #pragma unroll
        for (int c = 0; c < 4; ++c) { kt4[c] = ksrc[c]; vv4[c] = vsrc[c]; }

        __syncthreads();   // previous iteration done with Kt/Vs/Ps
        #pragma unroll
        for (int c = 0; c < 4; ++c) {
            Kt[dq + c*4 + 0][r] = kt4[c].x;
            Kt[dq + c*4 + 1][r] = kt4[c].y;
            Kt[dq + c*4 + 2][r] = kt4[c].z;
            Kt[dq + c*4 + 3][r] = kt4[c].w;
            *(float4*)&Vs[jr][seg + c*4] = vv4[c];
        }
        __syncthreads();

        // S = Q K^T  (64x64, reduce over d)
        float sv[4][4];
        #pragma unroll
        for (int i = 0; i < 4; ++i)
            #pragma unroll
            for (int j = 0; j < 4; ++j) sv[i][j] = 0.f;
        for (int d = 0; d < 64; ++d) {
            float4 qv = *(const float4*)&Qt[d][ty*4];
            float4 kv = *(const float4*)&Kt[d][tx*4];
            float qa[4] = {qv.x,qv.y,qv.z,qv.w};
            float ka[4] = {kv.x,kv.y,kv.z,kv.w};
            #pragma unroll
            for (int i = 0; i < 4; ++i)
                #pragma unroll
                for (int j = 0; j < 4; ++j)
                    sv[i][j] = fmaf(qa[i], ka[j], sv[i][j]);
        }

        const bool diag = (j0 == i0);
        #pragma unroll
        for (int i = 0; i < 4; ++i) {
            const int ig = i0 + ty*4 + i;
            float mx = -INFINITY;
            #pragma unroll
            for (int j = 0; j < 4; ++j) {
                float s = sv[i][j] * 0.125f;   // 1/sqrt(64)
                const int jg = j0 + tx*4 + j;
                if (diag && jg > ig) s = -INFINITY;
                sv[i][j] = s;
                mx = fmaxf(mx, s);
            }
            #pragma unroll
            for (int off = 1; off < 16; off <<= 1)
                mx = fmaxf(mx, __shfl_xor(mx, off, 64));
            const float mnew  = fmaxf(m_run[i], mx);
            const float alpha = __expf(m_run[i] - mnew);  // 0 on first tile
            float zs = 0.f, ds = 0.f;
            #pragma unroll
            for (int j = 0; j < 4; ++j) {
                const int jg = j0 + tx*4 + j;
                const float e = __expf(sv[i][j] - mnew);  // 0 for masked (-inf)
                float ep = 0.f;
                if (!diag || jg <= ig) ep = e * dtab[ig - jg];
                sv[i][j] = ep;
                zs += e; ds += ep;
            }
            #pragma unroll
            for (int off = 1; off < 16; off <<= 1) {
                zs += __shfl_xor(zs, off, 64);
                ds += __shfl_xor(ds, off, 64);
            }
            Zr[i]  = Zr[i]*alpha  + zs;
            den[i] = den[i]*alpha + ds;
            m_run[i] = mnew;
            #pragma unroll
            for (int j = 0; j < 4; ++j) acc[i][j] *= alpha;
        }

        // stage P' and accumulate O += P' V
        #pragma unroll
        for (int i = 0; i < 4; ++i)
            *(float4*)&Ps[ty*4+i][tx*4] = make_float4(sv[i][0], sv[i][1], sv[i][2], sv[i][3]);
        __syncthreads();

        for (int jq = 0; jq < 16; ++jq) {
            float4 p0 = *(const float4*)&Ps[ty*4+0][jq*4];
            float4 p1 = *(const float4*)&Ps[ty*4+1][jq*4];
            float4 p2 = *(const float4*)&Ps[ty*4+2][jq*4];
            float4 p3 = *(const float4*)&Ps[ty*4+3][jq*4];
            float4 v0 = *(const float4*)&Vs[jq*4+0][tx*4];
            float4 v1 = *(const float4*)&Vs[jq*4+1][tx*4];
            float4 v2 = *(const float4*)&Vs[jq*4+2][tx*4];
            float4 v3 = *(const float4*)&Vs[jq*4+3][tx*4];
            float pr[4][4] = {{p0.x,p0.y,p0.z,p0.w},{p1.x,p1.y,p1.z,p1.w},
                              {p2.x,p2.y,p2.z,p2.w},{p3.x,p3.y,p3.z,p3.w}};
            float vr[4][4] = {{v0.x,v0.y,v0.z,v0.w},{v1.x,v1.y,v1.z,v1.w},
                              {v2.x,v2.y,v2.z,v2.w},{v3.x,v3.y,v3.z,v3.w}};
            #pragma unroll
            for (int i = 0; i < 4; ++i)
                #pragma unroll
                for (int jj = 0; jj < 4; ++jj)
                    #pragma unroll
                    for (int dd = 0; dd < 4; ++dd)
                        acc[i][dd] = fmaf(pr[i][jj], vr[jj][dd], acc[i][dd]);
        }
    }

    // epilogue: y[b][t][h*64+d] = num / (den + 1e-8*Z)
    const int bb = bh / H_;
    #pragma unroll
    for (int i = 0; i < 4; ++i) {
        const float inv = 1.f / (den[i] + 1e-8f * Zr[i]);
        float4 o;
        o.x = acc[i][0]*inv; o.y = acc[i][1]*inv;
        o.z = acc[i][2]*inv; o.w = acc[i][3]*inv;
        *(float4*)&g_y[((size_t)(bb*T_ + i0 + ty*4 + i))*C_ + h*D_ + tx*4] = o;
    }
}

// ---------------------------------------------------------------------------
// Kernel 3: out = y @ W_proj + b_proj   (8192x768 @ 768x768)
// ---------------------------------------------------------------------------
__global__ __launch_bounds__(256) void k_proj_gemm(const float* __restrict__ W,
                                                   const float* __restrict__ bias,
                                                   float* __restrict__ out)
{
    __shared__ float As[16][132];
    __shared__ float Bs[16][128];

    const int tid = threadIdx.x;
    const int ty = tid >> 4;
    const int tx = tid & 15;
    const int m0 = blockIdx.x * 128;
    const int n0 = blockIdx.y * 128;

    const int ar = tid >> 2;
    const int ac = (tid & 3) * 4;
    const int br = tid >> 4;
    const int bc = (tid & 15) * 4;

    float acc[8][8];
    #pragma unroll
    for (int i = 0; i < 8; ++i)
        #pragma unroll
        for (int j = 0; j < 8; ++j) acc[i][j] = 0.f;

    for (int k0 = 0; k0 < C_; k0 += 16) {
        float4 a0 = *(const float4*)&g_y[(size_t)(m0+ar   )*C_ + k0 + ac];
        float4 a1 = *(const float4*)&g_y[(size_t)(m0+ar+64)*C_ + k0 + ac];
        float4 b0 = *(const float4*)&W[(size_t)(k0+br)*C_ + n0 + bc];
        float4 b1 = *(const float4*)&W[(size_t)(k0+br)*C_ + n0 + 64 + bc];
        __syncthreads();
        As[ac+0][ar   ] = a0.x; As[ac+1][ar   ] = a0.y; As[ac+2][ar   ] = a0.z; As[ac+3][ar   ] = a0.w;
        As[ac+0][ar+64] = a1.x; As[ac+1][ar+64] = a1.y; As[ac+2][ar+64] = a1.z; As[ac+3][ar+64] = a1.w;
        *(float4*)&Bs[br][bc]      = b0;
        *(float4*)&Bs[br][bc + 64] = b1;
        __syncthreads();
        #pragma unroll
        for (int kk = 0; kk < 16; ++kk) {
            float4 A0 = *(const float4*)&As[kk][ty*8];
            float4 A1 = *(const float4*)&As[kk][ty*8+4];
            float4 B0 = *(const float4*)&Bs[kk][tx*8];
            float4 B1 = *(const float4*)&Bs[kk][tx*8+4];
            float av[8] = {A0.x,A0.y,A0.z,A0.w,A1.x,A1.y,A1.z,A1.w};
            float bv[8] = {B0.x,B0.y,B0.z,B0.w,B1.x,B1.y,B1.z,B1.w};
            #pragma unroll
            for (int i = 0; i < 8; ++i)
                #pragma unroll
                for (int j = 0; j < 8; ++j)
                    acc[i][j] = fmaf(av[i], bv[j], acc[i][j]);
        }
    }

    float4 bias0 = *(const float4*)&bias[n0 + tx*8];
    float4 bias1 = *(const float4*)&bias[n0 + tx*8 + 4];
    #pragma unroll
    for (int i = 0; i < 8; ++i) {
        const int m = m0 + ty*8 + i;
        float4 o0, o1;
        o0.x = acc[i][0] + bias0.x; o0.y = acc[i][1] + bias0.y;
        o0.z = acc[i][2] + bias0.z; o0.w = acc[i][3] + bias0.w;
        o1.x = acc[i][4] + bias1.x; o1.y = acc[i][5] + bias1.y;
        o1.z = acc[i][6] + bias1.z; o1.w = acc[i][7] + bias1.w;
        *(float4*)&out[(size_t)m*C_ + n0 + tx*8]     = o0;
        *(float4*)&out[(size_t)m*C_ + n0 + tx*8 + 4] = o1;
    }
}

extern "C" void kernel_launch(void* const* d_in, const int* in_sizes, int n_in,
                              void* d_out, int out_size, void* d_ws, size_t ws_size,
                              hipStream_t stream) {
    (void)in_sizes; (void)n_in; (void)d_ws; (void)ws_size; (void)out_size;
    const float* x      = (const float*)d_in[0];
    const float* W_attn = (const float*)d_in[1];
    const float* b_attn = (const float*)d_in[2];
    const float* W_proj = (const float*)d_in[3];
    const float* b_proj = (const float*)d_in[4];
    const float* rates  = (const float*)d_in[5];
    float* out = (float*)d_out;

    dim3 g1(M_/128, QKV_N/128);          // 64 x 18
    hipLaunchKernelGGL(k_qkv_gemm, g1, dim3(256), 0, stream, x, W_attn, b_attn);

    dim3 g2(T_/64, B_*H_);               // 32 x 48
    hipLaunchKernelGGL(k_attn, g2, dim3(256), 0, stream, rates);

    dim3 g3(M_/128, C_/128);             // 64 x 6
    hipLaunchKernelGGL(k_proj_gemm, g3, dim3(256), 0, stream, W_proj, b_proj, out);
}

// Round 2
// 328.839 us; speedup vs baseline: 4.4601x; 4.4601x over previous
//
#include <hip/hip_runtime.h>
#include <math.h>

#define T_ 2048
#define C_ 768
#define H_ 12
#define D_ 64
#define M_ 8192
#define QKV_N 2304

typedef short bf16x8 __attribute__((ext_vector_type(8)));
typedef float f32x4 __attribute__((ext_vector_type(4)));
typedef unsigned short u16;
typedef u16 u16x8 __attribute__((ext_vector_type(8)));
typedef u16 u16x4 __attribute__((ext_vector_type(4)));

// Static device scratch (bf16 everywhere).
__device__ u16 g_q[M_*C_];   // [B*H][T][D]
__device__ u16 g_k[M_*C_];   // [B*H][T][D]
__device__ u16 g_vt[M_*C_];  // [B*H][D][T]  (V transposed for PV B-fragments)
__device__ u16 g_y[M_*C_];   // [B*T][C]     (attention output)

__device__ __forceinline__ u16 f2bf(float f) {
    unsigned u = __float_as_uint(f);
    return (u16)((u + 0x7FFFu + ((u >> 16) & 1u)) >> 16);   // RNE
}
__device__ __forceinline__ float bf2f(u16 h) {
    return __uint_as_float(((unsigned)h) << 16);
}
__device__ __forceinline__ f32x4 mfma16(bf16x8 a, bf16x8 b, f32x4 c) {
    return __builtin_amdgcn_mfma_f32_16x16x32_bf16(a, b, c, 0, 0, 0);
}

// ---------------------------------------------------------------------------
// Kernel 1: qkv = x @ W_attn + b_attn  (bf16 MFMA, fp32 inputs cvt on stage)
// 128x128 tile, BK=32, 4 waves (2x2), epilogue scatters bf16 q/k and V^T.
// ---------------------------------------------------------------------------
__global__ __launch_bounds__(256) void k_qkv(const float* __restrict__ x,
                                             const float* __restrict__ W,
                                             const float* __restrict__ bias)
{
    __shared__ u16 As[128][40];   // [m][k] pad+8 -> 2-way-free b128 reads
    __shared__ u16 Bs[128][40];   // [n][k] (B transposed in LDS)

    const int tid  = threadIdx.x;
    const int lane = tid & 63;
    const int wid  = tid >> 6;
    const int l15  = lane & 15;
    const int lg   = lane >> 4;
    const int wm = wid >> 1, wn = wid & 1;
    const int m0 = blockIdx.x * 128;
    const int n0 = blockIdx.y * 128;

    const int am = tid >> 1;            // 0..127 (A row)
    const int ak = (tid & 1) << 4;      // 0,16
    const int bn = tid & 127;           // B column
    const int bk = (tid >> 7) << 4;     // 0,16

    f32x4 acc[4][4];
    #pragma unroll
    for (int i = 0; i < 4; ++i)
        #pragma unroll
        for (int j = 0; j < 4; ++j) acc[i][j] = (f32x4){0.f,0.f,0.f,0.f};

    const float* apg = &x[(size_t)(m0+am)*C_ + ak];
    const float* bpg = &W[(size_t)bk*QKV_N + n0 + bn];

    for (int k0 = 0; k0 < C_; k0 += 32) {
        float4 a4[4];
        #pragma unroll
        for (int c = 0; c < 4; ++c) a4[c] = *(const float4*)(apg + k0 + c*4);
        float bv[16];
        #pragma unroll
        for (int kk = 0; kk < 16; ++kk) bv[kk] = bpg[(size_t)(k0+kk)*QKV_N];

        __syncthreads();
        {
            const float* af = (const float*)a4;
            u16x8 w0, w1, v0, v1;
            #pragma unroll
            for (int j = 0; j < 8; ++j) {
                w0[j] = f2bf(af[j]);  w1[j] = f2bf(af[j+8]);
                v0[j] = f2bf(bv[j]);  v1[j] = f2bf(bv[j+8]);
            }
            *(u16x8*)&As[am][ak]   = w0;  *(u16x8*)&As[am][ak+8] = w1;
            *(u16x8*)&Bs[bn][bk]   = v0;  *(u16x8*)&Bs[bn][bk+8] = v1;
        }
        __syncthreads();

        bf16x8 bfr[4];
        #pragma unroll
        for (int nt = 0; nt < 4; ++nt)
            bfr[nt] = *(const bf16x8*)&Bs[wn*64 + nt*16 + l15][lg*8];
        #pragma unroll
        for (int mt = 0; mt < 4; ++mt) {
            bf16x8 afr = *(const bf16x8*)&As[wm*64 + mt*16 + l15][lg*8];
            #pragma unroll
            for (int nt = 0; nt < 4; ++nt)
                acc[mt][nt] = mfma16(afr, bfr[nt], acc[mt][nt]);
        }
    }

    // Epilogue: nb is 64-aligned -> which/head constant per wave, d0 = 0.
    const int nb    = n0 + wn*64;
    const int which = nb / C_;             // 0=q 1=k 2=v
    const int h     = (nb % C_) / D_;
    const int mbase = m0 + wm*64;
    const int bb    = mbase >> 11;
    const int bh    = bb*H_ + h;
    float bv4[4];
    #pragma unroll
    for (int nt = 0; nt < 4; ++nt) bv4[nt] = bias[nb + nt*16 + l15];

    if (which == 2) {
        #pragma unroll
        for (int mt = 0; mt < 4; ++mt) {
            const int tb = (mbase + mt*16 + lg*4) & (T_-1);
            #pragma unroll
            for (int nt = 0; nt < 4; ++nt) {
                const int d = nt*16 + l15;
                u16x4 pk;
                #pragma unroll
                for (int r = 0; r < 4; ++r) pk[r] = f2bf(acc[mt][nt][r] + bv4[nt]);
                *(u16x4*)&g_vt[((size_t)bh*D_ + d)*T_ + tb] = pk;
            }
        }
    } else {
        u16* dst = which ? g_k : g_q;
        #pragma unroll
        for (int mt = 0; mt < 4; ++mt)
            #pragma unroll
            for (int r = 0; r < 4; ++r) {
                const int t = (mbase + mt*16 + lg*4 + r) & (T_-1);
                #pragma unroll
                for (int nt = 0; nt < 4; ++nt)
                    dst[((size_t)bh*T_ + t)*D_ + nt*16 + l15] = f2bf(acc[mt][nt][r] + bv4[nt]);
            }
    }
}

// ---------------------------------------------------------------------------
// Kernel 2: flash attention on decayed logits s' = s/8 - rate*(i-j).
// Block = (bh, q-tile pair {qt, 31-qt}) -> 33 uniform iters. 4 waves x 16 rows.
// ---------------------------------------------------------------------------
__global__ __launch_bounds__(256) void k_attn(const float* __restrict__ rates)
{
    __shared__ u16  Ks[64][72];    // [j][d] bf16, pad+8
    __shared__ u16  Vt[64][72];    // [d][j] bf16
    __shared__ float Ps[64][68];   // [i][j] fp32 P-tile (wave-private rows)

    const int tid  = threadIdx.x;
    const int lane = tid & 63;
    const int wid  = tid >> 6;
    const int l15  = lane & 15;
    const int lg   = lane >> 4;
    const int bh = blockIdx.y;
    const int h  = bh % H_;
    const int bb = bh / H_;
    const float rate = rates[h];

    const u16* qb  = &g_q[(size_t)bh * T_ * D_];
    const u16* kb  = &g_k[(size_t)bh * T_ * D_];
    const u16* vtb = &g_vt[(size_t)bh * D_ * T_];

    const int srow = tid >> 2;          // 0..63
    const int sc   = (tid & 3) << 4;    // 0,16,32,48

    #pragma unroll 1
    for (int half = 0; half < 2; ++half) {
        const int qt = half ? (31 - (int)blockIdx.x) : (int)blockIdx.x;
        const int i0 = qt * 64;

        bf16x8 qf[2];
        #pragma unroll
        for (int kf = 0; kf < 2; ++kf)
            qf[kf] = *(const bf16x8*)&qb[(size_t)(i0 + wid*16 + l15)*D_ + kf*32 + lg*8];

        f32x4 accO[4];
        float mrun[4], den[4];
        #pragma unroll
        for (int n = 0; n < 4; ++n) accO[n] = (f32x4){0.f,0.f,0.f,0.f};
        #pragma unroll
        for (int r = 0; r < 4; ++r) { mrun[r] = -INFINITY; den[r] = 0.f; }

        for (int j0 = 0; j0 <= i0; j0 += 64) {
            __syncthreads();
            *(u16x8*)&Ks[srow][sc]   = *(const u16x8*)&kb[(size_t)(j0+srow)*D_ + sc];
            *(u16x8*)&Ks[srow][sc+8] = *(const u16x8*)&kb[(size_t)(j0+srow)*D_ + sc + 8];
            *(u16x8*)&Vt[srow][sc]   = *(const u16x8*)&vtb[(size_t)srow*T_ + j0 + sc];
            *(u16x8*)&Vt[srow][sc+8] = *(const u16x8*)&vtb[(size_t)srow*T_ + j0 + sc + 8];
            __syncthreads();

            f32x4 accS[4];
            #pragma unroll
            for (int t = 0; t < 4; ++t) accS[t] = (f32x4){0.f,0.f,0.f,0.f};
            #pragma unroll
            for (int t = 0; t < 4; ++t)
                #pragma unroll
                for (int kf = 0; kf < 2; ++kf) {
                    bf16x8 kfr = *(const bf16x8*)&Ks[t*16 + l15][kf*32 + lg*8];
                    accS[t] = mfma16(qf[kf], kfr, accS[t]);
                }

            const bool diag = (j0 == i0);
            #pragma unroll
            for (int r = 0; r < 4; ++r) {
                const int ig = i0 + wid*16 + lg*4 + r;
                float sv[4];
                #pragma unroll
                for (int t = 0; t < 4; ++t) {
                    const int jg = j0 + t*16 + l15;
                    float s = accS[t][r] * 0.125f - rate * (float)(ig - jg);
                    if (diag && jg > ig) s = -INFINITY;
                    sv[t] = s;
                }
                float mx = fmaxf(fmaxf(sv[0], sv[1]), fmaxf(sv[2], sv[3]));
                #pragma unroll
                for (int m = 1; m < 16; m <<= 1)
                    mx = fmaxf(mx, __shfl_xor(mx, m, 64));
                const float mnew  = fmaxf(mrun[r], mx);
                const float alpha = __expf(mrun[r] - mnew);   // 0 on first tile
                mrun[r] = mnew;
                float zs = 0.f;
                #pragma unroll
                for (int t = 0; t < 4; ++t) {
                    const float p = __expf(sv[t] - mnew);
                    sv[t] = p;
                    zs += p;
                }
                #pragma unroll
                for (int m = 1; m < 16; m <<= 1)
                    zs += __shfl_xor(zs, m, 64);
                den[r] = den[r] * alpha + zs;
                #pragma unroll
                for (int n = 0; n < 4; ++n) accO[n][r] *= alpha;
                #pragma unroll
                for (int t = 0; t < 4; ++t)
                    Ps[wid*16 + lg*4 + r][t*16 + l15] = sv[t];
            }

            // PV: A-frags from wave-private Ps rows (same-wave LDS ordering).
            #pragma unroll
            for (int kf = 0; kf < 2; ++kf) {
                float pf[8];
                *(float4*)&pf[0] = *(const float4*)&Ps[wid*16 + l15][kf*32 + lg*8];
                *(float4*)&pf[4] = *(const float4*)&Ps[wid*16 + l15][kf*32 + lg*8 + 4];
                bf16x8 pa;
                #pragma unroll
                for (int j = 0; j < 8; ++j) pa[j] = (short)f2bf(pf[j]);
                #pragma unroll
                for (int n = 0; n < 4; ++n) {
                    bf16x8 vf = *(const bf16x8*)&Vt[n*16 + l15][kf*32 + lg*8];
                    accO[n] = mfma16(pa, vf, accO[n]);
                }
            }
        }

        #pragma unroll
        for (int r = 0; r < 4; ++r) {
            const float inv = 1.f / den[r];   // den >= 1 (online max of s')
            const int row = i0 + wid*16 + lg*4 + r;
            #pragma unroll
            for (int n = 0; n < 4; ++n)
                g_y[(size_t)(bb*T_ + row)*C_ + h*D_ + n*16 + l15] =
                    f2bf(accO[n][r] * inv);
        }
    }
}

// ---------------------------------------------------------------------------
// Kernel 3: out = y @ W_proj + b_proj (A=bf16 g_y; W split hi/lo bf16 pair
// for near-fp32 weight precision -> 2 MFMA per tile).
// ---------------------------------------------------------------------------
__global__ __launch_bounds__(256) void k_proj(const float* __restrict__ W,
                                              const float* __restrict__ bias,
                                              float* __restrict__ out)
{
    __shared__ u16 As[128][40];
    __shared__ u16 Bh[128][40];
    __shared__ u16 Bl[128][40];

    const int tid  = threadIdx.x;
    const int lane = tid & 63;
    const int wid  = tid >> 6;
    const int l15  = lane & 15;
    const int lg   = lane >> 4;
    const int wm = wid >> 1, wn = wid & 1;
    const int m0 = blockIdx.x * 128;
    const int n0 = blockIdx.y * 128;

    const int am = tid >> 1;
    const int ak = (tid & 1) << 4;
    const int bn = tid & 127;
    const int bk = (tid >> 7) << 4;

    f32x4 acc[4][4];
    #pragma unroll
    for (int i = 0; i < 4; ++i)
        #pragma unroll
        for (int j = 0; j < 4; ++j) acc[i][j] = (f32x4){0.f,0.f,0.f,0.f};

    const u16* apg = &g_y[(size_t)(m0+am)*C_ + ak];
    const float* bpg = &W[(size_t)bk*C_ + n0 + bn];

    for (int k0 = 0; k0 < C_; k0 += 32) {
        u16x8 a0 = *(const u16x8*)(apg + k0);
        u16x8 a1 = *(const u16x8*)(apg + k0 + 8);
        float bv[16];
        #pragma unroll
        for (int kk = 0; kk < 16; ++kk) bv[kk] = bpg[(size_t)(k0+kk)*C_];

        __syncthreads();
        {
            u16x8 h0, h1, l0, l1;
            #pragma unroll
            for (int j = 0; j < 8; ++j) {
                u16 hh = f2bf(bv[j]);
                h0[j] = hh; l0[j] = f2bf(bv[j] - bf2f(hh));
                hh = f2bf(bv[j+8]);
                h1[j] = hh; l1[j] = f2bf(bv[j+8] - bf2f(hh));
            }
            *(u16x8*)&As[am][ak]   = a0;  *(u16x8*)&As[am][ak+8] = a1;
            *(u16x8*)&Bh[bn][bk]   = h0;  *(u16x8*)&Bh[bn][bk+8] = h1;
            *(u16x8*)&Bl[bn][bk]   = l0;  *(u16x8*)&Bl[bn][bk+8] = l1;
        }
        __syncthreads();

        bf16x8 bh4[4], bl4[4];
        #pragma unroll
        for (int nt = 0; nt < 4; ++nt) {
            bh4[nt] = *(const bf16x8*)&Bh[wn*64 + nt*16 + l15][lg*8];
            bl4[nt] = *(const bf16x8*)&Bl[wn*64 + nt*16 + l15][lg*8];
        }
        #pragma unroll
        for (int mt = 0; mt < 4; ++mt) {
            bf16x8 afr = *(const bf16x8*)&As[wm*64 + mt*16 + l15][lg*8];
            #pragma unroll
            for (int nt = 0; nt < 4; ++nt) {
                acc[mt][nt] = mfma16(afr, bl4[nt], acc[mt][nt]);
                acc[mt][nt] = mfma16(afr, bh4[nt], acc[mt][nt]);
            }
        }
    }

    float bv4[4];
    #pragma unroll
    for (int nt = 0; nt < 4; ++nt) bv4[nt] = bias[n0 + wn*64 + nt*16 + l15];
    #pragma unroll
    for (int mt = 0; mt < 4; ++mt)
        #pragma unroll
        for (int r = 0; r < 4; ++r) {
            const int m = m0 + wm*64 + mt*16 + lg*4 + r;
            #pragma unroll
            for (int nt = 0; nt < 4; ++nt)
                out[(size_t)m*C_ + n0 + wn*64 + nt*16 + l15] = acc[mt][nt][r] + bv4[nt];
        }
}

extern "C" void kernel_launch(void* const* d_in, const int* in_sizes, int n_in,
                              void* d_out, int out_size, void* d_ws, size_t ws_size,
                              hipStream_t stream) {
    (void)in_sizes; (void)n_in; (void)d_ws; (void)ws_size; (void)out_size;
    const float* x      = (const float*)d_in[0];
    const float* W_attn = (const float*)d_in[1];
    const float* b_attn = (const float*)d_in[2];
    const float* W_proj = (const float*)d_in[3];
    const float* b_proj = (const float*)d_in[4];
    const float* rates  = (const float*)d_in[5];

    hipLaunchKernelGGL(k_qkv,  dim3(M_/128, QKV_N/128), dim3(256), 0, stream, x, W_attn, b_attn);
    hipLaunchKernelGGL(k_attn, dim3(16, 48),            dim3(256), 0, stream, rates);
    hipLaunchKernelGGL(k_proj, dim3(M_/128, C_/128),    dim3(256), 0, stream, W_proj, b_proj, (float*)d_out);
}

// Round 3
// 293.929 us; speedup vs baseline: 4.9898x; 1.1188x over previous
//
#include <hip/hip_runtime.h>
#include <hip/hip_bf16.h>
#include <math.h>

#define T_ 2048
#define C_ 768
#define H_ 12
#define D_ 64
#define M_ 8192
#define QKV_N 2304

typedef short bf16x8 __attribute__((ext_vector_type(8)));
typedef float f32x4 __attribute__((ext_vector_type(4)));
typedef unsigned short u16;
typedef u16 u16x8 __attribute__((ext_vector_type(8)));
typedef u16 u16x4 __attribute__((ext_vector_type(4)));

// Static device scratch.
__device__ u16 g_xb [M_*C_];      // x in bf16 [M][K]
__device__ u16 g_wat[QKV_N*C_];   // W_attn^T bf16 [N][K]
__device__ u16 g_wpt[C_*C_];      // W_proj^T bf16 [N][K]
__device__ u16 g_q [M_*C_];       // [B*H][T][D]
__device__ u16 g_k [M_*C_];       // [B*H][T][D]
__device__ u16 g_vt[M_*C_];       // [B*H][D][T]
__device__ u16 g_y [M_*C_];       // [B*T][C]

__device__ __forceinline__ u16 f2bf(float f) {
    return __bfloat16_as_ushort(__float2bfloat16(f));
}
__device__ __forceinline__ f32x4 mfma16(bf16x8 a, bf16x8 b, f32x4 c) {
    return __builtin_amdgcn_mfma_f32_16x16x32_bf16(a, b, c, 0, 0, 0);
}
// 16B-chunk XOR swizzle for [64-row][64-col] u16 LDS tiles (row stride 128B).
__device__ __forceinline__ int swz(int row, int col) {
    return row*64 + ((((col >> 3) ^ (row & 7))) << 3) + (col & 7);
}

// ---------------------------------------------------------------------------
// Prep: x -> bf16
// ---------------------------------------------------------------------------
__global__ __launch_bounds__(256) void k_prep_x(const float* __restrict__ x)
{
    const int idx = blockIdx.x*256 + threadIdx.x;          // grid covers M*C/8
    float4 a = ((const float4*)x)[idx*2];
    float4 b = ((const float4*)x)[idx*2+1];
    u16x8 o;
    o[0]=f2bf(a.x); o[1]=f2bf(a.y); o[2]=f2bf(a.z); o[3]=f2bf(a.w);
    o[4]=f2bf(b.x); o[5]=f2bf(b.y); o[6]=f2bf(b.z); o[7]=f2bf(b.w);
    ((u16x8*)g_xb)[idx] = o;
}

// ---------------------------------------------------------------------------
// Prep: W [K][N] f32 -> W^T [N][K] bf16   (which: 0 = W_attn, 1 = W_proj)
// ---------------------------------------------------------------------------
__global__ __launch_bounds__(256) void k_prep_wt(const float* __restrict__ src,
                                                 int which, int K, int N)
{
    __shared__ u16 L[64][72];
    const int tid = threadIdx.x;
    const int n0 = blockIdx.x*64, k0 = blockIdx.y*64;
    u16* dst = which ? g_wpt : g_wat;

    const int r  = tid >> 2;            // k row 0..63
    const int c0 = (tid & 3) * 16;      // n seg
    const float* p = &src[(size_t)(k0 + r)*N + n0 + c0];
    float4 v[4];
    #pragma unroll
    for (int c = 0; c < 4; ++c) v[c] = ((const float4*)p)[c];
    const float* vf = (const float*)v;
    #pragma unroll
    for (int j = 0; j < 16; ++j) L[c0 + j][r] = f2bf(vf[j]);
    __syncthreads();
    const int nn = tid >> 2;
    const int s  = (tid & 3) * 16;
    *(u16x8*)&dst[(size_t)(n0+nn)*K + k0 + s]     = *(const u16x8*)&L[nn][s];
    *(u16x8*)&dst[(size_t)(n0+nn)*K + k0 + s + 8] = *(const u16x8*)&L[nn][s+8];
}

// ---------------------------------------------------------------------------
// Kernel 1: qkv = x @ W_attn + b_attn (pure bf16 MFMA), scatter q/k and V^T.
// ---------------------------------------------------------------------------
__global__ __launch_bounds__(256) void k_qkv(const float* __restrict__ bias)
{
    __shared__ u16 As[128][40];
    __shared__ u16 Bs[128][40];

    const int tid  = threadIdx.x;
    const int lane = tid & 63;
    const int wid  = tid >> 6;
    const int l15  = lane & 15;
    const int lg   = lane >> 4;
    const int wm = wid >> 1, wn = wid & 1;
    const int m0 = blockIdx.x * 128;
    const int n0 = blockIdx.y * 128;

    const int sr = tid >> 2;            // row 0..63
    const int sc = (tid & 3) * 8;       // k offset

    f32x4 acc[4][4];
    #pragma unroll
    for (int i = 0; i < 4; ++i)
        #pragma unroll
        for (int j = 0; j < 4; ++j) acc[i][j] = (f32x4){0.f,0.f,0.f,0.f};

    for (int k0 = 0; k0 < C_; k0 += 32) {
        u16x8 a0 = *(const u16x8*)&g_xb [(size_t)(m0+sr    )*C_ + k0 + sc];
        u16x8 a1 = *(const u16x8*)&g_xb [(size_t)(m0+sr+64 )*C_ + k0 + sc];
        u16x8 b0 = *(const u16x8*)&g_wat[(size_t)(n0+sr    )*C_ + k0 + sc];
        u16x8 b1 = *(const u16x8*)&g_wat[(size_t)(n0+sr+64 )*C_ + k0 + sc];
        __syncthreads();
        *(u16x8*)&As[sr   ][sc] = a0;
        *(u16x8*)&As[sr+64][sc] = a1;
        *(u16x8*)&Bs[sr   ][sc] = b0;
        *(u16x8*)&Bs[sr+64][sc] = b1;
        __syncthreads();

        bf16x8 bfr[4];
        #pragma unroll
        for (int nt = 0; nt < 4; ++nt)
            bfr[nt] = *(const bf16x8*)&Bs[wn*64 + nt*16 + l15][lg*8];
        #pragma unroll
        for (int mt = 0; mt < 4; ++mt) {
            bf16x8 afr = *(const bf16x8*)&As[wm*64 + mt*16 + l15][lg*8];
            #pragma unroll
            for (int nt = 0; nt < 4; ++nt)
                acc[mt][nt] = mfma16(afr, bfr[nt], acc[mt][nt]);
        }
    }

    const int nb    = n0 + wn*64;
    const int which = nb / C_;
    const int h     = (nb % C_) / D_;
    const int mbase = m0 + wm*64;
    const int bb    = mbase >> 11;
    const int bh    = bb*H_ + h;
    float bv4[4];
    #pragma unroll
    for (int nt = 0; nt < 4; ++nt) bv4[nt] = bias[nb + nt*16 + l15];

    if (which == 2) {
        #pragma unroll
        for (int mt = 0; mt < 4; ++mt) {
            const int tb = (mbase + mt*16 + lg*4) & (T_-1);
            #pragma unroll
            for (int nt = 0; nt < 4; ++nt) {
                const int d = nt*16 + l15;
                u16x4 pk;
                #pragma unroll
                for (int r = 0; r < 4; ++r) pk[r] = f2bf(acc[mt][nt][r] + bv4[nt]);
                *(u16x4*)&g_vt[((size_t)bh*D_ + d)*T_ + tb] = pk;
            }
        }
    } else {
        u16* dst = which ? g_k : g_q;
        #pragma unroll
        for (int mt = 0; mt < 4; ++mt)
            #pragma unroll
            for (int r = 0; r < 4; ++r) {
                const int t = (mbase + mt*16 + lg*4 + r) & (T_-1);
                #pragma unroll
                for (int nt = 0; nt < 4; ++nt)
                    dst[((size_t)bh*T_ + t)*D_ + nt*16 + l15] = f2bf(acc[mt][nt][r] + bv4[nt]);
            }
    }
}

// ---------------------------------------------------------------------------
// Kernel 2: flash attention on decayed logits (exp2 domain).
// Swapped QK^T: lane owns one q-row. Each wave: 16 rows of BOTH halves of the
// {pr, 31-pr} q-tile pair, processed concurrently over a shared K/V stage.
// 1-D grid 768 with XCD-pinning decode.
// ---------------------------------------------------------------------------
__global__ __launch_bounds__(256) void k_attn(const float* __restrict__ rates)
{
    __shared__ u16 Ks[64*64];
    __shared__ u16 Vt[64*64];
    __shared__ u16 Ps[4][32*64];

    const int tid  = threadIdx.x;
    const int lane = tid & 63;
    const int wid  = tid >> 6;
    const int l15  = lane & 15;
    const int lg   = lane >> 4;

    const int id  = blockIdx.x;
    const int bh  = (id & 7)*6 + ((id >> 3) % 6);
    const int pr  = (id >> 3) / 6;
    const int h   = bh % H_;
    const int bb  = bh / H_;
    const float LOG2E  = 1.4426950408889634f;
    const float srate  = rates[h] * LOG2E;
    const float sscale = 0.125f * LOG2E;

    const int i0A = pr * 64;
    const int i0B = (31 - pr) * 64;
    const int igA = i0A + wid*16 + l15;
    const int igB = i0B + wid*16 + l15;
    const int thr = wid*16 + l15;

    const u16* qb  = &g_q [(size_t)bh*T_*D_];
    const u16* kb  = &g_k [(size_t)bh*T_*D_];
    const u16* vtb = &g_vt[(size_t)bh*D_*T_];

    bf16x8 qfA[2], qfB[2];
    #pragma unroll
    for (int kf = 0; kf < 2; ++kf) {
        qfA[kf] = *(const bf16x8*)&qb[(size_t)igA*D_ + kf*32 + lg*8];
        qfB[kf] = *(const bf16x8*)&qb[(size_t)igB*D_ + kf*32 + lg*8];
    }

    float joff[16];
    #pragma unroll
    for (int t = 0; t < 4; ++t)
        #pragma unroll
        for (int r = 0; r < 4; ++r) joff[t*4+r] = srate * (float)(t*16 + lg*4 + r);

    f32x4 oA[4], oB[4];
    #pragma unroll
    for (int n = 0; n < 4; ++n) { oA[n] = (f32x4){0,0,0,0}; oB[n] = (f32x4){0,0,0,0}; }
    float mA = -INFINITY, dA = 0.f, mB = -INFINITY, dB = 0.f;

    const int srow = tid >> 2;
    const int sc   = (tid & 3) * 16;
    u16x8 kp0 = *(const u16x8*)&kb[(size_t)srow*D_ + sc];
    u16x8 kp1 = *(const u16x8*)&kb[(size_t)srow*D_ + sc + 8];
    u16x8 vp0 = *(const u16x8*)&vtb[(size_t)srow*T_ + sc];
    u16x8 vp1 = *(const u16x8*)&vtb[(size_t)srow*T_ + sc + 8];

    u16* PsW = &Ps[wid][0];

    for (int j0 = 0; j0 <= i0B; j0 += 64) {
        __syncthreads();
        *(u16x8*)&Ks[swz(srow, sc)]     = kp0;
        *(u16x8*)&Ks[swz(srow, sc + 8)] = kp1;
        *(u16x8*)&Vt[swz(srow, sc)]     = vp0;
        *(u16x8*)&Vt[swz(srow, sc + 8)] = vp1;
        __syncthreads();
        const int jn = j0 + 64;
        if (jn <= i0B) {
            kp0 = *(const u16x8*)&kb[(size_t)(jn+srow)*D_ + sc];
            kp1 = *(const u16x8*)&kb[(size_t)(jn+srow)*D_ + sc + 8];
            vp0 = *(const u16x8*)&vtb[(size_t)srow*T_ + jn + sc];
            vp1 = *(const u16x8*)&vtb[(size_t)srow*T_ + jn + sc + 8];
        }
        const bool doA = (j0 <= i0A);

        f32x4 sA[4], sB[4];
        #pragma unroll
        for (int t = 0; t < 4; ++t) { sA[t] = (f32x4){0,0,0,0}; sB[t] = (f32x4){0,0,0,0}; }
        #pragma unroll
        for (int t = 0; t < 4; ++t)
            #pragma unroll
            for (int kf = 0; kf < 2; ++kf) {
                bf16x8 kfr = *(const bf16x8*)&Ks[swz(t*16 + l15, kf*32 + lg*8)];
                sB[t] = mfma16(kfr, qfB[kf], sB[t]);
                if (doA) sA[t] = mfma16(kfr, qfA[kf], sA[t]);
            }

        // ---- softmax group B (always) ----
        {
            const float c0 = srate * (float)(j0 - igB);
            const bool diag = (j0 == i0B);
            float p[16], mx = -INFINITY;
            #pragma unroll
            for (int t = 0; t < 4; ++t)
                #pragma unroll
                for (int r = 0; r < 4; ++r) {
                    float v = fmaf(sB[t][r], sscale, c0 + joff[t*4+r]);
                    if (diag && (t*16 + lg*4 + r > thr)) v = -INFINITY;
                    p[t*4+r] = v; mx = fmaxf(mx, v);
                }
            mx = fmaxf(mx, __shfl_xor(mx, 16, 64));
            mx = fmaxf(mx, __shfl_xor(mx, 32, 64));
            const float mnew = fmaxf(mB, mx);
            const float alpha = exp2f(mB - mnew);
            mB = mnew;
            float zs = 0.f;
            #pragma unroll
            for (int i = 0; i < 16; ++i) { float e = exp2f(p[i] - mnew); p[i] = e; zs += e; }
            zs += __shfl_xor(zs, 16, 64);
            zs += __shfl_xor(zs, 32, 64);
            dB = dB * alpha + zs;
            #pragma unroll
            for (int t = 0; t < 4; ++t) {
                u16x4 pk = { f2bf(p[t*4]), f2bf(p[t*4+1]), f2bf(p[t*4+2]), f2bf(p[t*4+3]) };
                *(u16x4*)&PsW[swz(16 + l15, t*16 + lg*4)] = pk;
            }
            float ar[4];
            #pragma unroll
            for (int r = 0; r < 4; ++r) ar[r] = __shfl(alpha, lg*4 + r, 64);
            #pragma unroll
            for (int n = 0; n < 4; ++n)
                #pragma unroll
                for (int r = 0; r < 4; ++r) oB[n][r] *= ar[r];
        }
        // ---- softmax group A ----
        if (doA) {
            const float c0 = srate * (float)(j0 - igA);
            const bool diag = (j0 == i0A);
            float p[16], mx = -INFINITY;
            #pragma unroll
            for (int t = 0; t < 4; ++t)
                #pragma unroll
                for (int r = 0; r < 4; ++r) {
                    float v = fmaf(sA[t][r], sscale, c0 + joff[t*4+r]);
                    if (diag && (t*16 + lg*4 + r > thr)) v = -INFINITY;
                    p[t*4+r] = v; mx = fmaxf(mx, v);
                }
            mx = fmaxf(mx, __shfl_xor(mx, 16, 64));
            mx = fmaxf(mx, __shfl_xor(mx, 32, 64));
            const float mnew = fmaxf(mA, mx);
            const float alpha = exp2f(mA - mnew);
            mA = mnew;
            float zs = 0.f;
            #pragma unroll
            for (int i = 0; i < 16; ++i) { float e = exp2f(p[i] - mnew); p[i] = e; zs += e; }
            zs += __shfl_xor(zs, 16, 64);
            zs += __shfl_xor(zs, 32, 64);
            dA = dA * alpha + zs;
            #pragma unroll
            for (int t = 0; t < 4; ++t) {
                u16x4 pk = { f2bf(p[t*4]), f2bf(p[t*4+1]), f2bf(p[t*4+2]), f2bf(p[t*4+3]) };
                *(u16x4*)&PsW[swz(l15, t*16 + lg*4)] = pk;
            }
            float ar[4];
            #pragma unroll
            for (int r = 0; r < 4; ++r) ar[r] = __shfl(alpha, lg*4 + r, 64);
            #pragma unroll
            for (int n = 0; n < 4; ++n)
                #pragma unroll
                for (int r = 0; r < 4; ++r) oA[n][r] *= ar[r];
        }

        // ---- PV ----
        #pragma unroll
        for (int kf = 0; kf < 2; ++kf) {
            bf16x8 paB = *(const bf16x8*)&PsW[swz(16 + l15, kf*32 + lg*8)];
            bf16x8 paA;
            if (doA) paA = *(const bf16x8*)&PsW[swz(l15, kf*32 + lg*8)];
            #pragma unroll
            for (int n = 0; n < 4; ++n) {
                bf16x8 vf = *(const bf16x8*)&Vt[swz(n*16 + l15, kf*32 + lg*8)];
                oB[n] = mfma16(paB, vf, oB[n]);
                if (doA) oA[n] = mfma16(paA, vf, oA[n]);
            }
        }
    }

    // ---- epilogue ----
    {
        const float inv = 1.f / dB;
        float ivr[4];
        #pragma unroll
        for (int r = 0; r < 4; ++r) ivr[r] = __shfl(inv, lg*4 + r, 64);
        #pragma unroll
        for (int r = 0; r < 4; ++r) {
            const int row = i0B + wid*16 + lg*4 + r;
            #pragma unroll
            for (int n = 0; n < 4; ++n)
                g_y[(size_t)(bb*T_ + row)*C_ + h*D_ + n*16 + l15] = f2bf(oB[n][r] * ivr[r]);
        }
    }
    {
        const float inv = 1.f / dA;
        float ivr[4];
        #pragma unroll
        for (int r = 0; r < 4; ++r) ivr[r] = __shfl(inv, lg*4 + r, 64);
        #pragma unroll
        for (int r = 0; r < 4; ++r) {
            const int row = i0A + wid*16 + lg*4 + r;
            #pragma unroll
            for (int n = 0; n < 4; ++n)
                g_y[(size_t)(bb*T_ + row)*C_ + h*D_ + n*16 + l15] = f2bf(oA[n][r] * ivr[r]);
        }
    }
}

// ---------------------------------------------------------------------------
// Kernel 3: out = y @ W_proj + b_proj (bf16 MFMA, fp32 out)
// ---------------------------------------------------------------------------
__global__ __launch_bounds__(256) void k_proj(const float* __restrict__ bias,
                                              float* __restrict__ out)
{
    __shared__ u16 As[128][40];
    __shared__ u16 Bs[128][40];

    const int tid  = threadIdx.x;
    const int lane = tid & 63;
    const int wid  = tid >> 6;
    const int l15  = lane & 15;
    const int lg   = lane >> 4;
    const int wm = wid >> 1, wn = wid & 1;
    const int m0 = blockIdx.x * 128;
    const int n0 = blockIdx.y * 128;

    const int sr = tid >> 2;
    const int sc = (tid & 3) * 8;

    f32x4 acc[4][4];
    #pragma unroll
    for (int i = 0; i < 4; ++i)
        #pragma unroll
        for (int j = 0; j < 4; ++j) acc[i][j] = (f32x4){0.f,0.f,0.f,0.f};

    for (int k0 = 0; k0 < C_; k0 += 32) {
        u16x8 a0 = *(const u16x8*)&g_y  [(size_t)(m0+sr   )*C_ + k0 + sc];
        u16x8 a1 = *(const u16x8*)&g_y  [(size_t)(m0+sr+64)*C_ + k0 + sc];
        u16x8 b0 = *(const u16x8*)&g_wpt[(size_t)(n0+sr   )*C_ + k0 + sc];
        u16x8 b1 = *(const u16x8*)&g_wpt[(size_t)(n0+sr+64)*C_ + k0 + sc];
        __syncthreads();
        *(u16x8*)&As[sr   ][sc] = a0;
        *(u16x8*)&As[sr+64][sc] = a1;
        *(u16x8*)&Bs[sr   ][sc] = b0;
        *(u16x8*)&Bs[sr+64][sc] = b1;
        __syncthreads();

        bf16x8 bfr[4];
        #pragma unroll
        for (int nt = 0; nt < 4; ++nt)
            bfr[nt] = *(const bf16x8*)&Bs[wn*64 + nt*16 + l15][lg*8];
        #pragma unroll
        for (int mt = 0; mt < 4; ++mt) {
            bf16x8 afr = *(const bf16x8*)&As[wm*64 + mt*16 + l15][lg*8];
            #pragma unroll
            for (int nt = 0; nt < 4; ++nt)
                acc[mt][nt] = mfma16(afr, bfr[nt], acc[mt][nt]);
        }
    }

    float bv4[4];
    #pragma unroll
    for (int nt = 0; nt < 4; ++nt) bv4[nt] = bias[n0 + wn*64 + nt*16 + l15];
    #pragma unroll
    for (int mt = 0; mt < 4; ++mt)
        #pragma unroll
        for (int r = 0; r < 4; ++r) {
            const int m = m0 + wm*64 + mt*16 + lg*4 + r;
            #pragma unroll
            for (int nt = 0; nt < 4; ++nt)
                out[(size_t)m*C_ + n0 + wn*64 + nt*16 + l15] = acc[mt][nt][r] + bv4[nt];
        }
}

extern "C" void kernel_launch(void* const* d_in, const int* in_sizes, int n_in,
                              void* d_out, int out_size, void* d_ws, size_t ws_size,
                              hipStream_t stream) {
    (void)in_sizes; (void)n_in; (void)d_ws; (void)ws_size; (void)out_size;
    const float* x      = (const float*)d_in[0];
    const float* W_attn = (const float*)d_in[1];
    const float* b_attn = (const float*)d_in[2];
    const float* W_proj = (const float*)d_in[3];
    const float* b_proj = (const float*)d_in[4];
    const float* rates  = (const float*)d_in[5];

    hipLaunchKernelGGL(k_prep_x,  dim3(M_*C_/8/256), dim3(256), 0, stream, x);
    hipLaunchKernelGGL(k_prep_wt, dim3(QKV_N/64, C_/64), dim3(256), 0, stream, W_attn, 0, C_, QKV_N);
    hipLaunchKernelGGL(k_prep_wt, dim3(C_/64,    C_/64), dim3(256), 0, stream, W_proj, 1, C_, C_);
    hipLaunchKernelGGL(k_qkv,  dim3(M_/128, QKV_N/128), dim3(256), 0, stream, b_attn);
    hipLaunchKernelGGL(k_attn, dim3(768),               dim3(256), 0, stream, rates);
    hipLaunchKernelGGL(k_proj, dim3(M_/128, C_/128),    dim3(256), 0, stream, b_proj, (float*)d_out);
}

// Round 5
// 218.960 us; speedup vs baseline: 6.6983x; 1.3424x over previous
//
#include <hip/hip_runtime.h>
#include <hip/hip_bf16.h>
#include <math.h>

#define T_ 2048
#define C_ 768
#define H_ 12
#define D_ 64
#define M_ 8192
#define QKV_N 2304

typedef short bf16x8 __attribute__((ext_vector_type(8)));
typedef float f32x4 __attribute__((ext_vector_type(4)));
typedef unsigned short u16;
typedef u16 u16x8 __attribute__((ext_vector_type(8)));
typedef u16 u16x4 __attribute__((ext_vector_type(4)));

// Static device scratch.
__device__ u16 g_xb [M_*C_];      // x in bf16 [M][K]
__device__ u16 g_wat[QKV_N*C_];   // W_attn^T bf16 [N][K]
__device__ u16 g_wpt[C_*C_];      // W_proj^T bf16 [N][K]
__device__ u16 g_q [M_*C_];       // [B*H][T][D]
__device__ u16 g_k [M_*C_];       // [B*H][T][D]
__device__ u16 g_vt[M_*C_];       // [B*H][D][T]
__device__ u16 g_y [M_*C_];       // [B*T][C]

__device__ __forceinline__ u16 f2bf(float f) {
    return __bfloat16_as_ushort(__float2bfloat16(f));
}
__device__ __forceinline__ f32x4 mfma16(bf16x8 a, bf16x8 b, f32x4 c) {
    return __builtin_amdgcn_mfma_f32_16x16x32_bf16(a, b, c, 0, 0, 0);
}
// 16B-chunk XOR swizzle for 64-col u16 LDS tiles (row stride 128B).
__device__ __forceinline__ int swz(int row, int col) {
    return row*64 + ((((col >> 3) ^ (row & 7))) << 3) + (col & 7);
}

// ---------------------------------------------------------------------------
// Prep: x -> bf16
// ---------------------------------------------------------------------------
__global__ __launch_bounds__(256) void k_prep_x(const float* __restrict__ x)
{
    const int idx = blockIdx.x*256 + threadIdx.x;          // grid covers M*C/8
    float4 a = ((const float4*)x)[idx*2];
    float4 b = ((const float4*)x)[idx*2+1];
    u16x8 o;
    o[0]=f2bf(a.x); o[1]=f2bf(a.y); o[2]=f2bf(a.z); o[3]=f2bf(a.w);
    o[4]=f2bf(b.x); o[5]=f2bf(b.y); o[6]=f2bf(b.z); o[7]=f2bf(b.w);
    ((u16x8*)g_xb)[idx] = o;
}

// ---------------------------------------------------------------------------
// Prep: W [K][N] f32 -> W^T [N][K] bf16   (which: 0 = W_attn, 1 = W_proj)
// ---------------------------------------------------------------------------
__global__ __launch_bounds__(256) void k_prep_wt(const float* __restrict__ src,
                                                 int which, int K, int N)
{
    __shared__ u16 L[64][72];
    const int tid = threadIdx.x;
    const int n0 = blockIdx.x*64, k0 = blockIdx.y*64;
    u16* dst = which ? g_wpt : g_wat;

    const int r  = tid >> 2;            // k row 0..63
    const int c0 = (tid & 3) * 16;      // n seg
    const float* p = &src[(size_t)(k0 + r)*N + n0 + c0];
    float4 v[4];
    #pragma unroll
    for (int c = 0; c < 4; ++c) v[c] = ((const float4*)p)[c];
    const float* vf = (const float*)v;
    #pragma unroll
    for (int j = 0; j < 16; ++j) L[c0 + j][r] = f2bf(vf[j]);
    __syncthreads();
    const int nn = tid >> 2;
    const int s  = (tid & 3) * 16;
    *(u16x8*)&dst[(size_t)(n0+nn)*K + k0 + s]     = *(const u16x8*)&L[nn][s];
    *(u16x8*)&dst[(size_t)(n0+nn)*K + k0 + s + 8] = *(const u16x8*)&L[nn][s+8];
}

// ---------------------------------------------------------------------------
// Kernel 1: qkv = x @ W_attn + b_attn (pure bf16 MFMA), scatter q/k and V^T.
// ---------------------------------------------------------------------------
__global__ __launch_bounds__(256) void k_qkv(const float* __restrict__ bias)
{
    __shared__ u16 As[128][40];
    __shared__ u16 Bs[128][40];

    const int tid  = threadIdx.x;
    const int lane = tid & 63;
    const int wid  = tid >> 6;
    const int l15  = lane & 15;
    const int lg   = lane >> 4;
    const int wm = wid >> 1, wn = wid & 1;
    const int m0 = blockIdx.x * 128;
    const int n0 = blockIdx.y * 128;

    const int sr = tid >> 2;            // row 0..63
    const int sc = (tid & 3) * 8;       // k offset

    f32x4 acc[4][4];
    #pragma unroll
    for (int i = 0; i < 4; ++i)
        #pragma unroll
        for (int j = 0; j < 4; ++j) acc[i][j] = (f32x4){0.f,0.f,0.f,0.f};

    for (int k0 = 0; k0 < C_; k0 += 32) {
        u16x8 a0 = *(const u16x8*)&g_xb [(size_t)(m0+sr    )*C_ + k0 + sc];
        u16x8 a1 = *(const u16x8*)&g_xb [(size_t)(m0+sr+64 )*C_ + k0 + sc];
        u16x8 b0 = *(const u16x8*)&g_wat[(size_t)(n0+sr    )*C_ + k0 + sc];
        u16x8 b1 = *(const u16x8*)&g_wat[(size_t)(n0+sr+64 )*C_ + k0 + sc];
        __syncthreads();
        *(u16x8*)&As[sr   ][sc] = a0;
        *(u16x8*)&As[sr+64][sc] = a1;
        *(u16x8*)&Bs[sr   ][sc] = b0;
        *(u16x8*)&Bs[sr+64][sc] = b1;
        __syncthreads();

        bf16x8 bfr[4];
        #pragma unroll
        for (int nt = 0; nt < 4; ++nt)
            bfr[nt] = *(const bf16x8*)&Bs[wn*64 + nt*16 + l15][lg*8];
        #pragma unroll
        for (int mt = 0; mt < 4; ++mt) {
            bf16x8 afr = *(const bf16x8*)&As[wm*64 + mt*16 + l15][lg*8];
            #pragma unroll
            for (int nt = 0; nt < 4; ++nt)
                acc[mt][nt] = mfma16(afr, bfr[nt], acc[mt][nt]);
        }
    }

    const int nb    = n0 + wn*64;
    const int which = nb / C_;
    const int h     = (nb % C_) / D_;
    const int mbase = m0 + wm*64;
    const int bb    = mbase >> 11;
    const int bh    = bb*H_ + h;
    float bv4[4];
    #pragma unroll
    for (int nt = 0; nt < 4; ++nt) bv4[nt] = bias[nb + nt*16 + l15];

    if (which == 2) {
        #pragma unroll
        for (int mt = 0; mt < 4; ++mt) {
            const int tb = (mbase + mt*16 + lg*4) & (T_-1);
            #pragma unroll
            for (int nt = 0; nt < 4; ++nt) {
                const int d = nt*16 + l15;
                u16x4 pk;
                #pragma unroll
                for (int r = 0; r < 4; ++r) pk[r] = f2bf(acc[mt][nt][r] + bv4[nt]);
                *(u16x4*)&g_vt[((size_t)bh*D_ + d)*T_ + tb] = pk;
            }
        }
    } else {
        u16* dst = which ? g_k : g_q;
        #pragma unroll
        for (int mt = 0; mt < 4; ++mt)
            #pragma unroll
            for (int r = 0; r < 4; ++r) {
                const int t = (mbase + mt*16 + lg*4 + r) & (T_-1);
                #pragma unroll
                for (int nt = 0; nt < 4; ++nt)
                    dst[((size_t)bh*T_ + t)*D_ + nt*16 + l15] = f2bf(acc[mt][nt][r] + bv4[nt]);
            }
    }
}

// ---------------------------------------------------------------------------
// Kernel 2: windowed flash attention on decayed logits, reverse iteration,
// fixed reference-max (no online rescale). Block = 64 q-rows, 4 waves x 16.
// Window: decay guarantees tiles beyond ~(34.4/rate) positions contribute
// < 2^-26 relative -> provably below bf16 noise. Computed per-head on device.
// ---------------------------------------------------------------------------
__global__ __launch_bounds__(256) void k_attn(const float* __restrict__ rates)
{
    __shared__ u16 Ks[64*64];
    __shared__ u16 Vt[64*64];
    __shared__ u16 Ps[4][16*64];

    const int tid  = threadIdx.x;
    const int lane = tid & 63;
    const int wid  = tid >> 6;
    const int l15  = lane & 15;
    const int lg   = lane >> 4;

    const int id  = blockIdx.x;
    const int bh  = (id & 7)*6 + ((id >> 3) % 6);
    const int qt  = 31 - ((id >> 3) / 6);      // big windows dispatch first
    const int h   = bh % H_;
    const int bb  = bh / H_;
    const float rate = rates[h];
    const float LOG2E  = 1.4426950408889634f;
    const float srate  = rate * LOG2E;
    const float sscale = 0.125f * LOG2E;

    const int i0  = qt * 64;
    const int thr = wid*16 + l15;              // q-row in block this lane owns
    const int ig  = i0 + thr;

    // decay window (tiles): keep while rate*delta < G(=16) + ln(1e8)
    const int wt = (int)(34.4f / (fmaxf(rate, 1e-8f) * 64.0f)) + 2;
    const int nT = min(qt + 1, wt);

    const u16* qb  = &g_q [(size_t)bh*T_*D_];
    const u16* kb  = &g_k [(size_t)bh*T_*D_];
    const u16* vtb = &g_vt[(size_t)bh*D_*T_];

    bf16x8 qf[2];
    qf[0] = *(const bf16x8*)&qb[(size_t)ig*D_ + lg*8];
    qf[1] = *(const bf16x8*)&qb[(size_t)ig*D_ + 32 + lg*8];

    float joff[16];
    #pragma unroll
    for (int t = 0; t < 4; ++t)
        #pragma unroll
        for (int r = 0; r < 4; ++r) joff[t*4+r] = srate * (float)(t*16 + lg*4 + r);

    f32x4 oAcc[4];
    #pragma unroll
    for (int n = 0; n < 4; ++n) oAcc[n] = (f32x4){0.f,0.f,0.f,0.f};
    float den = 0.f, mrow = 0.f;

    const int srow = tid >> 2;
    const int sc   = (tid & 3) << 4;

    // prefetch diagonal tile
    u16x8 kp0 = *(const u16x8*)&kb[(size_t)(i0+srow)*D_ + sc];
    u16x8 kp1 = *(const u16x8*)&kb[(size_t)(i0+srow)*D_ + sc + 8];
    u16x8 vp0 = *(const u16x8*)&vtb[(size_t)srow*T_ + i0 + sc];
    u16x8 vp1 = *(const u16x8*)&vtb[(size_t)srow*T_ + i0 + sc + 8];

    u16* PsW = &Ps[wid][0];

    for (int tt = 0; tt < nT; ++tt) {
        const int j0 = i0 - tt*64;
        __syncthreads();
        *(u16x8*)&Ks[swz(srow, sc)]     = kp0;
        *(u16x8*)&Ks[swz(srow, sc + 8)] = kp1;
        *(u16x8*)&Vt[swz(srow, sc)]     = vp0;
        *(u16x8*)&Vt[swz(srow, sc + 8)] = vp1;
        __syncthreads();
        if (tt + 1 < nT) {
            const int jn = j0 - 64;
            kp0 = *(const u16x8*)&kb[(size_t)(jn+srow)*D_ + sc];
            kp1 = *(const u16x8*)&kb[(size_t)(jn+srow)*D_ + sc + 8];
            vp0 = *(const u16x8*)&vtb[(size_t)srow*T_ + jn + sc];
            vp1 = *(const u16x8*)&vtb[(size_t)srow*T_ + jn + sc + 8];
        }

        // QK^T (swapped: A=K, B=Q -> lane owns q-row l15 across 16 j regs)
        __builtin_amdgcn_s_setprio(1);
        f32x4 sAcc[4];
        #pragma unroll
        for (int t = 0; t < 4; ++t) sAcc[t] = (f32x4){0.f,0.f,0.f,0.f};
        #pragma unroll
        for (int t = 0; t < 4; ++t)
            #pragma unroll
            for (int kf = 0; kf < 2; ++kf) {
                bf16x8 kfr = *(const bf16x8*)&Ks[swz(t*16 + l15, kf*32 + lg*8)];
                sAcc[t] = mfma16(kfr, qf[kf], sAcc[t]);
            }
        __builtin_amdgcn_s_setprio(0);

        float e[16];
        if (tt == 0) {
            // diagonal tile: mask, take row max ONCE as the fixed reference
            const float sth = srate * (float)thr;
            float pv[16];
            float mx = -3e38f;
            #pragma unroll
            for (int t = 0; t < 4; ++t)
                #pragma unroll
                for (int r = 0; r < 4; ++r) {
                    const int jj = t*16 + lg*4 + r;
                    float v = fmaf(sAcc[t][r], sscale, joff[t*4+r] - sth);
                    if (jj > thr) v = -3e38f;
                    pv[t*4+r] = v;
                    mx = fmaxf(mx, v);
                }
            mx = fmaxf(mx, __shfl_xor(mx, 16, 64));
            mx = fmaxf(mx, __shfl_xor(mx, 32, 64));
            mrow = mx;
            #pragma unroll
            for (int i = 0; i < 16; ++i) {
                e[i] = __builtin_amdgcn_exp2f(pv[i] - mx);
                den += e[i];
            }
        } else {
            // fast path: no mask, no max tracking; fold m into the constant
            const float c0m = fmaf(srate, (float)(j0 - ig), -mrow);
            #pragma unroll
            for (int t = 0; t < 4; ++t)
                #pragma unroll
                for (int r = 0; r < 4; ++r) {
                    const float v = fmaf(sAcc[t][r], sscale, c0m + joff[t*4+r]);
                    const float p = __builtin_amdgcn_exp2f(v);
                    e[t*4+r] = p;
                    den += p;
                }
        }

        // pack P (bf16) into wave-private LDS rows
        #pragma unroll
        for (int t = 0; t < 4; ++t) {
            u16x4 pk = { f2bf(e[t*4]), f2bf(e[t*4+1]), f2bf(e[t*4+2]), f2bf(e[t*4+3]) };
            *(u16x4*)&PsW[swz(l15, t*16 + lg*4)] = pk;
        }

        // PV
        __builtin_amdgcn_s_setprio(1);
        #pragma unroll
        for (int kf = 0; kf < 2; ++kf) {
            bf16x8 pa = *(const bf16x8*)&PsW[swz(l15, kf*32 + lg*8)];
            #pragma unroll
            for (int n = 0; n < 4; ++n) {
                bf16x8 vf = *(const bf16x8*)&Vt[swz(n*16 + l15, kf*32 + lg*8)];
                oAcc[n] = mfma16(pa, vf, oAcc[n]);
            }
        }
        __builtin_amdgcn_s_setprio(0);
    }

    // single end-of-loop reduction + normalize + store
    den += __shfl_xor(den, 16, 64);
    den += __shfl_xor(den, 32, 64);
    const float inv = 1.f / den;
    float ivr[4];
    #pragma unroll
    for (int r = 0; r < 4; ++r) ivr[r] = __shfl(inv, lg*4 + r, 64);
    #pragma unroll
    for (int r = 0; r < 4; ++r) {
        const int row = i0 + wid*16 + lg*4 + r;
        #pragma unroll
        for (int n = 0; n < 4; ++n)
            g_y[(size_t)(bb*T_ + row)*C_ + h*D_ + n*16 + l15] = f2bf(oAcc[n][r] * ivr[r]);
    }
}

// ---------------------------------------------------------------------------
// Kernel 3: out = y @ W_proj + b_proj (bf16 MFMA, fp32 out)
// ---------------------------------------------------------------------------
__global__ __launch_bounds__(256) void k_proj(const float* __restrict__ bias,
                                              float* __restrict__ out)
{
    __shared__ u16 As[128][40];
    __shared__ u16 Bs[128][40];

    const int tid  = threadIdx.x;
    const int lane = tid & 63;
    const int wid  = tid >> 6;
    const int l15  = lane & 15;
    const int lg   = lane >> 4;
    const int wm = wid >> 1, wn = wid & 1;
    const int m0 = blockIdx.x * 128;
    const int n0 = blockIdx.y * 128;

    const int sr = tid >> 2;
    const int sc = (tid & 3) * 8;

    f32x4 acc[4][4];
    #pragma unroll
    for (int i = 0; i < 4; ++i)
        #pragma unroll
        for (int j = 0; j < 4; ++j) acc[i][j] = (f32x4){0.f,0.f,0.f,0.f};

    for (int k0 = 0; k0 < C_; k0 += 32) {
        u16x8 a0 = *(const u16x8*)&g_y  [(size_t)(m0+sr   )*C_ + k0 + sc];
        u16x8 a1 = *(const u16x8*)&g_y  [(size_t)(m0+sr+64)*C_ + k0 + sc];
        u16x8 b0 = *(const u16x8*)&g_wpt[(size_t)(n0+sr   )*C_ + k0 + sc];
        u16x8 b1 = *(const u16x8*)&g_wpt[(size_t)(n0+sr+64)*C_ + k0 + sc];
        __syncthreads();
        *(u16x8*)&As[sr   ][sc] = a0;
        *(u16x8*)&As[sr+64][sc] = a1;
        *(u16x8*)&Bs[sr   ][sc] = b0;
        *(u16x8*)&Bs[sr+64][sc] = b1;
        __syncthreads();

        bf16x8 bfr[4];
        #pragma unroll
        for (int nt = 0; nt < 4; ++nt)
            bfr[nt] = *(const bf16x8*)&Bs[wn*64 + nt*16 + l15][lg*8];
        #pragma unroll
        for (int mt = 0; mt < 4; ++mt) {
            bf16x8 afr = *(const bf16x8*)&As[wm*64 + mt*16 + l15][lg*8];
            #pragma unroll
            for (int nt = 0; nt < 4; ++nt)
                acc[mt][nt] = mfma16(afr, bfr[nt], acc[mt][nt]);
        }
    }

    float bv4[4];
    #pragma unroll
    for (int nt = 0; nt < 4; ++nt) bv4[nt] = bias[n0 + wn*64 + nt*16 + l15];
    #pragma unroll
    for (int mt = 0; mt < 4; ++mt)
        #pragma unroll
        for (int r = 0; r < 4; ++r) {
            const int m = m0 + wm*64 + mt*16 + lg*4 + r;
            #pragma unroll
            for (int nt = 0; nt < 4; ++nt)
                out[(size_t)m*C_ + n0 + wn*64 + nt*16 + l15] = acc[mt][nt][r] + bv4[nt];
        }
}

extern "C" void kernel_launch(void* const* d_in, const int* in_sizes, int n_in,
                              void* d_out, int out_size, void* d_ws, size_t ws_size,
                              hipStream_t stream) {
    (void)in_sizes; (void)n_in; (void)d_ws; (void)ws_size; (void)out_size;
    const float* x      = (const float*)d_in[0];
    const float* W_attn = (const float*)d_in[1];
    const float* b_attn = (const float*)d_in[2];
    const float* W_proj = (const float*)d_in[3];
    const float* b_proj = (const float*)d_in[4];
    const float* rates  = (const float*)d_in[5];

    hipLaunchKernelGGL(k_prep_x,  dim3(M_*C_/8/256), dim3(256), 0, stream, x);
    hipLaunchKernelGGL(k_prep_wt, dim3(QKV_N/64, C_/64), dim3(256), 0, stream, W_attn, 0, C_, QKV_N);
    hipLaunchKernelGGL(k_prep_wt, dim3(C_/64,    C_/64), dim3(256), 0, stream, W_proj, 1, C_, C_);
    hipLaunchKernelGGL(k_qkv,  dim3(M_/128, QKV_N/128), dim3(256), 0, stream, b_attn);
    hipLaunchKernelGGL(k_attn, dim3(1536),              dim3(256), 0, stream, rates);
    hipLaunchKernelGGL(k_proj, dim3(M_/128, C_/128),    dim3(256), 0, stream, b_proj, (float*)d_out);
}

// Round 7
// 206.209 us; speedup vs baseline: 7.1125x; 1.0618x over previous
//
#include <hip/hip_runtime.h>
#include <hip/hip_bf16.h>
#include <math.h>

#define T_ 2048
#define C_ 768
#define H_ 12
#define D_ 64
#define M_ 8192
#define QKV_N 2304

typedef short bf16x8 __attribute__((ext_vector_type(8)));
typedef float f32x4 __attribute__((ext_vector_type(4)));
typedef unsigned short u16;
typedef u16 u16x8 __attribute__((ext_vector_type(8)));
typedef u16 u16x4 __attribute__((ext_vector_type(4)));

// Static device scratch.
__device__ u16 g_xb [M_*C_];      // x in bf16 [M][K]
__device__ u16 g_wat[QKV_N*C_];   // W_attn^T bf16 [N][K]
__device__ u16 g_wpt[C_*C_];      // W_proj^T bf16 [N][K]
__device__ u16 g_q [M_*C_];       // [B*H][T][D]
__device__ u16 g_k [M_*C_];       // [B*H][T][D]
__device__ u16 g_vt[M_*C_];       // [B*H][D][T]
__device__ u16 g_y [M_*C_];       // [B*T][C]

__device__ __forceinline__ u16 f2bf(float f) {
    return __bfloat16_as_ushort(__float2bfloat16(f));
}
__device__ __forceinline__ f32x4 mfma16(bf16x8 a, bf16x8 b, f32x4 c) {
    return __builtin_amdgcn_mfma_f32_16x16x32_bf16(a, b, c, 0, 0, 0);
}
// async global->LDS, 16B per lane; LDS dest = wave-uniform base + lane*16 (HW).
__device__ __forceinline__ void gl16(const u16* g, u16* l) {
    __builtin_amdgcn_global_load_lds(
        (const __attribute__((address_space(1))) unsigned int*)g,
        (__attribute__((address_space(3))) unsigned int*)l, 16, 0, 0);
}
// LDS tiles are [rows][64 u16] linear; data is chunk-swizzled: position chunk p
// at row r holds logical k-chunk (p ^ (r&7)). Read of logical chunk c:
__device__ __forceinline__ int ridx(int row, int chunk) {
    return row*64 + (((chunk) ^ (row & 7)) << 3);
}
// byte-level swizzle helper for sub-chunk writes (Ps): col in u16 units
__device__ __forceinline__ int swz(int row, int col) {
    return row*64 + ((((col >> 3) ^ (row & 7))) << 3) + (col & 7);
}

// ---------------------------------------------------------------------------
// Prep: x -> bf16
// ---------------------------------------------------------------------------
__global__ __launch_bounds__(256) void k_prep_x(const float* __restrict__ x)
{
    const int idx = blockIdx.x*256 + threadIdx.x;          // grid covers M*C/8
    float4 a = ((const float4*)x)[idx*2];
    float4 b = ((const float4*)x)[idx*2+1];
    u16x8 o;
    o[0]=f2bf(a.x); o[1]=f2bf(a.y); o[2]=f2bf(a.z); o[3]=f2bf(a.w);
    o[4]=f2bf(b.x); o[5]=f2bf(b.y); o[6]=f2bf(b.z); o[7]=f2bf(b.w);
    ((u16x8*)g_xb)[idx] = o;
}

// ---------------------------------------------------------------------------
// Prep: W [K][N] f32 -> W^T [N][K] bf16   (which: 0 = W_attn, 1 = W_proj)
// ---------------------------------------------------------------------------
__global__ __launch_bounds__(256) void k_prep_wt(const float* __restrict__ src,
                                                 int which, int K, int N)
{
    __shared__ u16 L[64][72];
    const int tid = threadIdx.x;
    const int n0 = blockIdx.x*64, k0 = blockIdx.y*64;
    u16* dst = which ? g_wpt : g_wat;

    const int r  = tid >> 2;            // k row 0..63
    const int c0 = (tid & 3) * 16;      // n seg
    const float* p = &src[(size_t)(k0 + r)*N + n0 + c0];
    float4 v[4];
    #pragma unroll
    for (int c = 0; c < 4; ++c) v[c] = ((const float4*)p)[c];
    const float* vf = (const float*)v;
    #pragma unroll
    for (int j = 0; j < 16; ++j) L[c0 + j][r] = f2bf(vf[j]);
    __syncthreads();
    const int nn = tid >> 2;
    const int s  = (tid & 3) * 16;
    *(u16x8*)&dst[(size_t)(n0+nn)*K + k0 + s]     = *(const u16x8*)&L[nn][s];
    *(u16x8*)&dst[(size_t)(n0+nn)*K + k0 + s + 8] = *(const u16x8*)&L[nn][s+8];
}

// ---------------------------------------------------------------------------
// Kernel 1: qkv = x @ W_attn + b_attn. 128x128 tile, BK=64, global_load_lds
// staging with pre-swizzled source; scatter q/k and V^T epilogue.
// ---------------------------------------------------------------------------
__global__ __launch_bounds__(256) void k_qkv(const float* __restrict__ bias)
{
    __shared__ u16 As[128*64];
    __shared__ u16 Bs[128*64];

    const int tid  = threadIdx.x;
    const int lane = tid & 63;
    const int wid  = tid >> 6;
    const int l15  = lane & 15;
    const int lg   = lane >> 4;
    const int wm = wid >> 1, wn = wid & 1;
    const int m0 = blockIdx.x * 128;
    const int n0 = blockIdx.y * 128;

    const int srow8 = lane >> 3;              // 0..7 (row within 8-row issue)
    const int schk  = (lane & 7) ^ srow8;     // pre-swizzled source chunk

    f32x4 acc[4][4];
    #pragma unroll
    for (int i = 0; i < 4; ++i)
        #pragma unroll
        for (int j = 0; j < 4; ++j) acc[i][j] = (f32x4){0.f,0.f,0.f,0.f};

    for (int k0 = 0; k0 < C_; k0 += 64) {
        __syncthreads();                      // prior compute done with LDS
        #pragma unroll
        for (int i = 0; i < 4; ++i) {
            const int r = wid*32 + i*8;
            gl16(&g_xb [(size_t)(m0 + r + srow8)*C_ + k0 + (schk<<3)], &As[r*64]);
            gl16(&g_wat[(size_t)(n0 + r + srow8)*C_ + k0 + (schk<<3)], &Bs[r*64]);
        }
        __syncthreads();                      // vmcnt(0) drain + barrier
        #pragma unroll
        for (int kf = 0; kf < 2; ++kf) {
            bf16x8 bfr[4];
            #pragma unroll
            for (int nt = 0; nt < 4; ++nt) {
                const int rw = wn*64 + nt*16 + l15;
                bfr[nt] = *(const bf16x8*)&Bs[ridx(rw, kf*4 + lg)];
            }
            #pragma unroll
            for (int mt = 0; mt < 4; ++mt) {
                const int rw = wm*64 + mt*16 + l15;
                bf16x8 afr = *(const bf16x8*)&As[ridx(rw, kf*4 + lg)];
                #pragma unroll
                for (int nt = 0; nt < 4; ++nt)
                    acc[mt][nt] = mfma16(afr, bfr[nt], acc[mt][nt]);
            }
        }
    }

    const int nb    = n0 + wn*64;
    const int which = nb / C_;
    const int h     = (nb % C_) / D_;
    const int mbase = m0 + wm*64;
    const int bb    = mbase >> 11;
    const int bh    = bb*H_ + h;
    float bv4[4];
    #pragma unroll
    for (int nt = 0; nt < 4; ++nt) bv4[nt] = bias[nb + nt*16 + l15];

    if (which == 2) {
        #pragma unroll
        for (int mt = 0; mt < 4; ++mt) {
            const int tb = (mbase + mt*16 + lg*4) & (T_-1);
            #pragma unroll
            for (int nt = 0; nt < 4; ++nt) {
                const int d = nt*16 + l15;
                u16x4 pk;
                #pragma unroll
                for (int r = 0; r < 4; ++r) pk[r] = f2bf(acc[mt][nt][r] + bv4[nt]);
                *(u16x4*)&g_vt[((size_t)bh*D_ + d)*T_ + tb] = pk;
            }
        }
    } else {
        u16* dst = which ? g_k : g_q;
        #pragma unroll
        for (int mt = 0; mt < 4; ++mt)
            #pragma unroll
            for (int r = 0; r < 4; ++r) {
                const int t = (mbase + mt*16 + lg*4 + r) & (T_-1);
                #pragma unroll
                for (int nt = 0; nt < 4; ++nt)
                    dst[((size_t)bh*T_ + t)*D_ + nt*16 + l15] = f2bf(acc[mt][nt][r] + bv4[nt]);
            }
    }
}

// ---------------------------------------------------------------------------
// Kernel 2: windowed flash attention on decayed logits, reverse iteration,
// fixed reference-max. Staging via global_load_lds (pre-swizzled source).
// ---------------------------------------------------------------------------
__global__ __launch_bounds__(256) void k_attn(const float* __restrict__ rates)
{
    __shared__ u16 Ks[64*64];
    __shared__ u16 Vt[64*64];
    __shared__ u16 Ps[4][16*64];

    const int tid  = threadIdx.x;
    const int lane = tid & 63;
    const int wid  = tid >> 6;
    const int l15  = lane & 15;
    const int lg   = lane >> 4;

    const int id  = blockIdx.x;
    const int bh  = (id & 7)*6 + ((id >> 3) % 6);
    const int qt  = 31 - ((id >> 3) / 6);      // big windows dispatch first
    const int h   = bh % H_;
    const int bb  = bh / H_;
    const float rate = rates[h];
    const float LOG2E  = 1.4426950408889634f;
    const float srate  = rate * LOG2E;
    const float sscale = 0.125f * LOG2E;

    const int i0  = qt * 64;
    const int thr = wid*16 + l15;              // q-row in block this lane owns
    const int ig  = i0 + thr;

    // decay window (tiles): keep while rate*delta < G(=16) + ln(1e8)
    const int wt = (int)(34.4f / (fmaxf(rate, 1e-8f) * 64.0f)) + 2;
    const int nT = min(qt + 1, wt);

    const u16* qb  = &g_q [(size_t)bh*T_*D_];
    const u16* kb  = &g_k [(size_t)bh*T_*D_];
    const u16* vtb = &g_vt[(size_t)bh*D_*T_];

    bf16x8 qf[2];
    qf[0] = *(const bf16x8*)&qb[(size_t)ig*D_ + lg*8];
    qf[1] = *(const bf16x8*)&qb[(size_t)ig*D_ + 32 + lg*8];

    float joff[16];
    #pragma unroll
    for (int t = 0; t < 4; ++t)
        #pragma unroll
        for (int r = 0; r < 4; ++r) joff[t*4+r] = srate * (float)(t*16 + lg*4 + r);

    f32x4 oAcc[4];
    #pragma unroll
    for (int n = 0; n < 4; ++n) oAcc[n] = (f32x4){0.f,0.f,0.f,0.f};
    float den = 0.f, mrow = 0.f;

    const int srow8 = lane >> 3;
    const int schk  = (lane & 7) ^ srow8;

    u16* PsW = &Ps[wid][0];

    for (int tt = 0; tt < nT; ++tt) {
        const int j0 = i0 - tt*64;
        __syncthreads();                       // prev compute done with Ks/Vt
        #pragma unroll
        for (int i = 0; i < 2; ++i) {
            const int r = wid*16 + i*8;        // K rows / V d-rows this issue
            gl16(&kb [(size_t)(j0 + r + srow8)*D_ + (schk<<3)], &Ks[r*64]);
            gl16(&vtb[(size_t)(r + srow8)*T_ + j0 + (schk<<3)], &Vt[r*64]);
        }
        __syncthreads();                       // vmcnt(0) drain + barrier

        // QK^T (swapped: A=K, B=Q -> lane owns q-row l15 across 16 j regs)
        __builtin_amdgcn_s_setprio(1);
        f32x4 sAcc[4];
        #pragma unroll
        for (int t = 0; t < 4; ++t) sAcc[t] = (f32x4){0.f,0.f,0.f,0.f};
        #pragma unroll
        for (int t = 0; t < 4; ++t)
            #pragma unroll
            for (int kf = 0; kf < 2; ++kf) {
                bf16x8 kfr = *(const bf16x8*)&Ks[ridx(t*16 + l15, kf*4 + lg)];
                sAcc[t] = mfma16(kfr, qf[kf], sAcc[t]);
            }
        __builtin_amdgcn_s_setprio(0);

        float e[16];
        if (tt == 0) {
            // diagonal tile: mask, take row max ONCE as the fixed reference
            const float sth = srate * (float)thr;
            float pv[16];
            float mx = -3e38f;
            #pragma unroll
            for (int t = 0; t < 4; ++t)
                #pragma unroll
                for (int r = 0; r < 4; ++r) {
                    const int jj = t*16 + lg*4 + r;
                    float v = fmaf(sAcc[t][r], sscale, joff[t*4+r] - sth);
                    if (jj > thr) v = -3e38f;
                    pv[t*4+r] = v;
                    mx = fmaxf(mx, v);
                }
            mx = fmaxf(mx, __shfl_xor(mx, 16, 64));
            mx = fmaxf(mx, __shfl_xor(mx, 32, 64));
            mrow = mx;
            #pragma unroll
            for (int i = 0; i < 16; ++i) {
                e[i] = __builtin_amdgcn_exp2f(pv[i] - mx);
                den += e[i];
            }
        } else {
            // fast path: no mask, no max tracking; fold m into the constant
            const float c0m = fmaf(srate, (float)(j0 - ig), -mrow);
            #pragma unroll
            for (int t = 0; t < 4; ++t)
                #pragma unroll
                for (int r = 0; r < 4; ++r) {
                    const float v = fmaf(sAcc[t][r], sscale, c0m + joff[t*4+r]);
                    const float p = __builtin_amdgcn_exp2f(v);
                    e[t*4+r] = p;
                    den += p;
                }
        }

        // pack P (bf16) into wave-private LDS rows
        #pragma unroll
        for (int t = 0; t < 4; ++t) {
            u16x4 pk = { f2bf(e[t*4]), f2bf(e[t*4+1]), f2bf(e[t*4+2]), f2bf(e[t*4+3]) };
            *(u16x4*)&PsW[swz(l15, t*16 + lg*4)] = pk;
        }

        // PV
        __builtin_amdgcn_s_setprio(1);
        #pragma unroll
        for (int kf = 0; kf < 2; ++kf) {
            bf16x8 pa = *(const bf16x8*)&PsW[ridx(l15, kf*4 + lg)];
            #pragma unroll
            for (int n = 0; n < 4; ++n) {
                bf16x8 vf = *(const bf16x8*)&Vt[ridx(n*16 + l15, kf*4 + lg)];
                oAcc[n] = mfma16(pa, vf, oAcc[n]);
            }
        }
        __builtin_amdgcn_s_setprio(0);
    }

    // single end-of-loop reduction + normalize + store
    den += __shfl_xor(den, 16, 64);
    den += __shfl_xor(den, 32, 64);
    const float inv = 1.f / den;
    float ivr[4];
    #pragma unroll
    for (int r = 0; r < 4; ++r) ivr[r] = __shfl(inv, lg*4 + r, 64);
    #pragma unroll
    for (int r = 0; r < 4; ++r) {
        const int row = i0 + wid*16 + lg*4 + r;
        #pragma unroll
        for (int n = 0; n < 4; ++n)
            g_y[(size_t)(bb*T_ + row)*C_ + h*D_ + n*16 + l15] = f2bf(oAcc[n][r] * ivr[r]);
    }
}

// ---------------------------------------------------------------------------
// Kernel 3: out = y @ W_proj + b_proj (same structure as k_qkv, fp32 out)
// ---------------------------------------------------------------------------
__global__ __launch_bounds__(256) void k_proj(const float* __restrict__ bias,
                                              float* __restrict__ out)
{
    __shared__ u16 As[128*64];
    __shared__ u16 Bs[128*64];

    const int tid  = threadIdx.x;
    const int lane = tid & 63;
    const int wid  = tid >> 6;
    const int l15  = lane & 15;
    const int lg   = lane >> 4;
    const int wm = wid >> 1, wn = wid & 1;
    const int m0 = blockIdx.x * 128;
    const int n0 = blockIdx.y * 128;

    const int srow8 = lane >> 3;
    const int schk  = (lane & 7) ^ srow8;

    f32x4 acc[4][4];
    #pragma unroll
    for (int i = 0; i < 4; ++i)
        #pragma unroll
        for (int j = 0; j < 4; ++j) acc[i][j] = (f32x4){0.f,0.f,0.f,0.f};

    for (int k0 = 0; k0 < C_; k0 += 64) {
        __syncthreads();
        #pragma unroll
        for (int i = 0; i < 4; ++i) {
            const int r = wid*32 + i*8;
            gl16(&g_y  [(size_t)(m0 + r + srow8)*C_ + k0 + (schk<<3)], &As[r*64]);
            gl16(&g_wpt[(size_t)(n0 + r + srow8)*C_ + k0 + (schk<<3)], &Bs[r*64]);
        }
        __syncthreads();
        #pragma unroll
        for (int kf = 0; kf < 2; ++kf) {
            bf16x8 bfr[4];
            #pragma unroll
            for (int nt = 0; nt < 4; ++nt) {
                const int rw = wn*64 + nt*16 + l15;
                bfr[nt] = *(const bf16x8*)&Bs[ridx(rw, kf*4 + lg)];
            }
            #pragma unroll
            for (int mt = 0; mt < 4; ++mt) {
                const int rw = wm*64 + mt*16 + l15;
                bf16x8 afr = *(const bf16x8*)&As[ridx(rw, kf*4 + lg)];
                #pragma unroll
                for (int nt = 0; nt < 4; ++nt)
                    acc[mt][nt] = mfma16(afr, bfr[nt], acc[mt][nt]);
            }
        }
    }

    float bv4[4];
    #pragma unroll
    for (int nt = 0; nt < 4; ++nt) bv4[nt] = bias[n0 + wn*64 + nt*16 + l15];
    #pragma unroll
    for (int mt = 0; mt < 4; ++mt)
        #pragma unroll
        for (int r = 0; r < 4; ++r) {
            const int m = m0 + wm*64 + mt*16 + lg*4 + r;
            #pragma unroll
            for (int nt = 0; nt < 4; ++nt)
                out[(size_t)m*C_ + n0 + wn*64 + nt*16 + l15] = acc[mt][nt][r] + bv4[nt];
        }
}

extern "C" void kernel_launch(void* const* d_in, const int* in_sizes, int n_in,
                              void* d_out, int out_size, void* d_ws, size_t ws_size,
                              hipStream_t stream) {
    (void)in_sizes; (void)n_in; (void)d_ws; (void)ws_size; (void)out_size;
    const float* x      = (const float*)d_in[0];
    const float* W_attn = (const float*)d_in[1];
    const float* b_attn = (const float*)d_in[2];
    const float* W_proj = (const float*)d_in[3];
    const float* b_proj = (const float*)d_in[4];
    const float* rates  = (const float*)d_in[5];

    hipLaunchKernelGGL(k_prep_x,  dim3(M_*C_/8/256), dim3(256), 0, stream, x);
    hipLaunchKernelGGL(k_prep_wt, dim3(QKV_N/64, C_/64), dim3(256), 0, stream, W_attn, 0, C_, QKV_N);
    hipLaunchKernelGGL(k_prep_wt, dim3(C_/64,    C_/64), dim3(256), 0, stream, W_proj, 1, C_, C_);
    hipLaunchKernelGGL(k_qkv,  dim3(M_/128, QKV_N/128), dim3(256), 0, stream, b_attn);
    hipLaunchKernelGGL(k_attn, dim3(1536),              dim3(256), 0, stream, rates);
    hipLaunchKernelGGL(k_proj, dim3(M_/128, C_/128),    dim3(256), 0, stream, b_proj, (float*)d_out);
}

// Round 8
// 196.096 us; speedup vs baseline: 7.4792x; 1.0516x over previous
//
#include <hip/hip_runtime.h>
#include <hip/hip_bf16.h>
#include <math.h>

#define T_ 2048
#define C_ 768
#define H_ 12
#define D_ 64
#define M_ 8192
#define QKV_N 2304

typedef short bf16x8 __attribute__((ext_vector_type(8)));
typedef float f32x4 __attribute__((ext_vector_type(4)));
typedef unsigned short u16;
typedef u16 u16x8 __attribute__((ext_vector_type(8)));
typedef u16 u16x4 __attribute__((ext_vector_type(4)));

// Static device scratch.
__device__ u16 g_xb [M_*C_];      // x in bf16 [M][K]
__device__ u16 g_wat[QKV_N*C_];   // W_attn^T bf16 [N][K]
__device__ u16 g_wpt[C_*C_];      // W_proj^T bf16 [N][K]
__device__ u16 g_q [M_*C_];       // [B*H][T][D]
__device__ u16 g_k [M_*C_];       // [B*H][T][D]
__device__ u16 g_vt[M_*C_];       // [B*H][D][T]
__device__ u16 g_y [M_*C_];       // [B*T][C]

__device__ __forceinline__ u16 f2bf(float f) {
    return __bfloat16_as_ushort(__float2bfloat16(f));
}
__device__ __forceinline__ f32x4 mfma16(bf16x8 a, bf16x8 b, f32x4 c) {
    return __builtin_amdgcn_mfma_f32_16x16x32_bf16(a, b, c, 0, 0, 0);
}
// async global->LDS, 16B per lane; LDS dest = wave-uniform base + lane*16 (HW).
__device__ __forceinline__ void gl16(const u16* g, u16* l) {
    __builtin_amdgcn_global_load_lds(
        (const __attribute__((address_space(1))) unsigned int*)g,
        (__attribute__((address_space(3))) unsigned int*)l, 16, 0, 0);
}
// LDS tiles are [rows][64 u16] linear; data is chunk-swizzled: position chunk p
// at row r holds logical k-chunk (p ^ (r&7)). Read of logical chunk c:
__device__ __forceinline__ int ridx(int row, int chunk) {
    return row*64 + (((chunk) ^ (row & 7)) << 3);
}
// byte-level swizzle helper for sub-chunk writes (Ps): col in u16 units
__device__ __forceinline__ int swz(int row, int col) {
    return row*64 + ((((col >> 3) ^ (row & 7))) << 3) + (col & 7);
}

// ---------------------------------------------------------------------------
// Prep: x -> bf16
// ---------------------------------------------------------------------------
__global__ __launch_bounds__(256) void k_prep_x(const float* __restrict__ x)
{
    const int idx = blockIdx.x*256 + threadIdx.x;          // grid covers M*C/8
    float4 a = ((const float4*)x)[idx*2];
    float4 b = ((const float4*)x)[idx*2+1];
    u16x8 o;
    o[0]=f2bf(a.x); o[1]=f2bf(a.y); o[2]=f2bf(a.z); o[3]=f2bf(a.w);
    o[4]=f2bf(b.x); o[5]=f2bf(b.y); o[6]=f2bf(b.z); o[7]=f2bf(b.w);
    ((u16x8*)g_xb)[idx] = o;
}

// ---------------------------------------------------------------------------
// Prep: W [K][N] f32 -> W^T [N][K] bf16. One launch covers W_attn (x<36)
// and W_proj (x>=36).
// ---------------------------------------------------------------------------
__global__ __launch_bounds__(256) void k_prep_w(const float* __restrict__ Wa,
                                                const float* __restrict__ Wp)
{
    __shared__ u16 L[64][72];
    const int tid = threadIdx.x;
    const int bx  = blockIdx.x;
    const int which = (bx >= QKV_N/64);
    const float* src = which ? Wp : Wa;
    const int N = which ? C_ : QKV_N;
    u16* dst = which ? g_wpt : g_wat;
    const int n0 = (which ? bx - QKV_N/64 : bx) * 64;
    const int k0 = blockIdx.y * 64;

    const int r  = tid >> 2;            // k row 0..63
    const int c0 = (tid & 3) * 16;      // n seg
    const float* p = &src[(size_t)(k0 + r)*N + n0 + c0];
    float4 v[4];
    #pragma unroll
    for (int c = 0; c < 4; ++c) v[c] = ((const float4*)p)[c];
    const float* vf = (const float*)v;
    #pragma unroll
    for (int j = 0; j < 16; ++j) L[c0 + j][r] = f2bf(vf[j]);
    __syncthreads();
    const int nn = tid >> 2;
    const int s  = (tid & 3) * 16;
    *(u16x8*)&dst[(size_t)(n0+nn)*C_ + k0 + s]     = *(const u16x8*)&L[nn][s];
    *(u16x8*)&dst[(size_t)(n0+nn)*C_ + k0 + s + 8] = *(const u16x8*)&L[nn][s+8];
}

// ---------------------------------------------------------------------------
// Kernel 1: qkv = x @ W_attn + b_attn. 128x128 tile, BK=64, double-buffered
// global_load_lds staging (T3 2-phase prefetch); scatter q/k and V^T epilogue.
// ---------------------------------------------------------------------------
__global__ __launch_bounds__(256) void k_qkv(const float* __restrict__ bias)
{
    __shared__ u16 As[2][128*64];
    __shared__ u16 Bs[2][128*64];

    const int tid  = threadIdx.x;
    const int lane = tid & 63;
    const int wid  = tid >> 6;
    const int l15  = lane & 15;
    const int lg   = lane >> 4;
    const int wm = wid >> 1, wn = wid & 1;
    const int m0 = blockIdx.x * 128;
    const int n0 = blockIdx.y * 128;

    const int srow8 = lane >> 3;              // 0..7 (row within 8-row issue)
    const int schk  = (lane & 7) ^ srow8;     // pre-swizzled source chunk

    f32x4 acc[4][4];
    #pragma unroll
    for (int i = 0; i < 4; ++i)
        #pragma unroll
        for (int j = 0; j < 4; ++j) acc[i][j] = (f32x4){0.f,0.f,0.f,0.f};

    const u16* xa = &g_xb [(size_t)(m0 + wid*32 + srow8)*C_ + (schk<<3)];
    const u16* wb = &g_wat[(size_t)(n0 + wid*32 + srow8)*C_ + (schk<<3)];

    // prologue: stage k-tile 0 into buffer 0
    #pragma unroll
    for (int i = 0; i < 4; ++i) {
        const int r = wid*32 + i*8;
        gl16(xa + (size_t)i*8*C_,       &As[0][r*64]);
        gl16(wb + (size_t)i*8*C_,       &Bs[0][r*64]);
    }
    __syncthreads();                          // vmcnt(0) drain + barrier

    int cur = 0;
    for (int k = 0; k < 12; ++k) {
        if (k < 11) {                         // prefetch next k-tile
            const int ko = (k+1)*64;
            #pragma unroll
            for (int i = 0; i < 4; ++i) {
                const int r = wid*32 + i*8;
                gl16(xa + (size_t)i*8*C_ + ko, &As[cur^1][r*64]);
                gl16(wb + (size_t)i*8*C_ + ko, &Bs[cur^1][r*64]);
            }
        }
        __builtin_amdgcn_s_setprio(1);
        #pragma unroll
        for (int kf = 0; kf < 2; ++kf) {
            bf16x8 bfr[4];
            #pragma unroll
            for (int nt = 0; nt < 4; ++nt) {
                const int rw = wn*64 + nt*16 + l15;
                bfr[nt] = *(const bf16x8*)&Bs[cur][ridx(rw, kf*4 + lg)];
            }
            #pragma unroll
            for (int mt = 0; mt < 4; ++mt) {
                const int rw = wm*64 + mt*16 + l15;
                bf16x8 afr = *(const bf16x8*)&As[cur][ridx(rw, kf*4 + lg)];
                #pragma unroll
                for (int nt = 0; nt < 4; ++nt)
                    acc[mt][nt] = mfma16(afr, bfr[nt], acc[mt][nt]);
            }
        }
        __builtin_amdgcn_s_setprio(0);
        __syncthreads();                      // drain next-tile loads + reads
        cur ^= 1;
    }

    const int nb    = n0 + wn*64;
    const int which = nb / C_;
    const int h     = (nb % C_) / D_;
    const int mbase = m0 + wm*64;
    const int bb    = mbase >> 11;
    const int bh    = bb*H_ + h;
    float bv4[4];
    #pragma unroll
    for (int nt = 0; nt < 4; ++nt) bv4[nt] = bias[nb + nt*16 + l15];

    if (which == 2) {
        #pragma unroll
        for (int mt = 0; mt < 4; ++mt) {
            const int tb = (mbase + mt*16 + lg*4) & (T_-1);
            #pragma unroll
            for (int nt = 0; nt < 4; ++nt) {
                const int d = nt*16 + l15;
                u16x4 pk;
                #pragma unroll
                for (int r = 0; r < 4; ++r) pk[r] = f2bf(acc[mt][nt][r] + bv4[nt]);
                *(u16x4*)&g_vt[((size_t)bh*D_ + d)*T_ + tb] = pk;
            }
        }
    } else {
        u16* dst = which ? g_k : g_q;
        #pragma unroll
        for (int mt = 0; mt < 4; ++mt)
            #pragma unroll
            for (int r = 0; r < 4; ++r) {
                const int t = (mbase + mt*16 + lg*4 + r) & (T_-1);
                #pragma unroll
                for (int nt = 0; nt < 4; ++nt)
                    dst[((size_t)bh*T_ + t)*D_ + nt*16 + l15] = f2bf(acc[mt][nt][r] + bv4[nt]);
            }
    }
}

// ---------------------------------------------------------------------------
// Kernel 2: windowed flash attention on decayed logits, reverse iteration,
// fixed reference-max, double-buffered K/V staging (T3 2-phase prefetch).
// ---------------------------------------------------------------------------
__global__ __launch_bounds__(256) void k_attn(const float* __restrict__ rates)
{
    __shared__ u16 Ks[2][64*64];
    __shared__ u16 Vt[2][64*64];
    __shared__ u16 Ps[4][16*64];

    const int tid  = threadIdx.x;
    const int lane = tid & 63;
    const int wid  = tid >> 6;
    const int l15  = lane & 15;
    const int lg   = lane >> 4;

    const int id  = blockIdx.x;
    const int bh  = (id & 7)*6 + ((id >> 3) % 6);
    const int qt  = 31 - ((id >> 3) / 6);      // big windows dispatch first
    const int h   = bh % H_;
    const int bb  = bh / H_;
    const float rate = rates[h];
    const float LOG2E  = 1.4426950408889634f;
    const float srate  = rate * LOG2E;
    const float sscale = 0.125f * LOG2E;

    const int i0  = qt * 64;
    const int thr = wid*16 + l15;              // q-row in block this lane owns
    const int ig  = i0 + thr;

    // decay window (tiles): keep while rate*delta < G(=16) + ln(1e8)
    const int wt = (int)(34.4f / (fmaxf(rate, 1e-8f) * 64.0f)) + 2;
    const int nT = min(qt + 1, wt);

    const u16* qb  = &g_q [(size_t)bh*T_*D_];
    const u16* kb  = &g_k [(size_t)bh*T_*D_];
    const u16* vtb = &g_vt[(size_t)bh*D_*T_];

    bf16x8 qf[2];
    qf[0] = *(const bf16x8*)&qb[(size_t)ig*D_ + lg*8];
    qf[1] = *(const bf16x8*)&qb[(size_t)ig*D_ + 32 + lg*8];

    float joff[16];
    #pragma unroll
    for (int t = 0; t < 4; ++t)
        #pragma unroll
        for (int r = 0; r < 4; ++r) joff[t*4+r] = srate * (float)(t*16 + lg*4 + r);

    f32x4 oAcc[4];
    #pragma unroll
    for (int n = 0; n < 4; ++n) oAcc[n] = (f32x4){0.f,0.f,0.f,0.f};
    float den = 0.f, mrow = 0.f;

    const int srow8 = lane >> 3;
    const int schk  = (lane & 7) ^ srow8;

    u16* PsW = &Ps[wid][0];

    // prologue: stage diagonal tile into buffer 0
    #pragma unroll
    for (int i = 0; i < 2; ++i) {
        const int r = wid*16 + i*8;
        gl16(&kb [(size_t)(i0 + r + srow8)*D_ + (schk<<3)], &Ks[0][r*64]);
        gl16(&vtb[(size_t)(r + srow8)*T_ + i0 + (schk<<3)], &Vt[0][r*64]);
    }
    __syncthreads();

    int cur = 0;
    for (int tt = 0; tt < nT; ++tt) {
        const int j0 = i0 - tt*64;
        if (tt + 1 < nT) {                     // prefetch next (older) tile
            const int jn = j0 - 64;
            #pragma unroll
            for (int i = 0; i < 2; ++i) {
                const int r = wid*16 + i*8;
                gl16(&kb [(size_t)(jn + r + srow8)*D_ + (schk<<3)], &Ks[cur^1][r*64]);
                gl16(&vtb[(size_t)(r + srow8)*T_ + jn + (schk<<3)], &Vt[cur^1][r*64]);
            }
        }

        // QK^T (swapped: A=K, B=Q -> lane owns q-row l15 across 16 j regs)
        __builtin_amdgcn_s_setprio(1);
        f32x4 sAcc[4];
        #pragma unroll
        for (int t = 0; t < 4; ++t) sAcc[t] = (f32x4){0.f,0.f,0.f,0.f};
        #pragma unroll
        for (int t = 0; t < 4; ++t)
            #pragma unroll
            for (int kf = 0; kf < 2; ++kf) {
                bf16x8 kfr = *(const bf16x8*)&Ks[cur][ridx(t*16 + l15, kf*4 + lg)];
                sAcc[t] = mfma16(kfr, qf[kf], sAcc[t]);
            }
        __builtin_amdgcn_s_setprio(0);

        float e[16];
        if (tt == 0) {
            // diagonal tile: mask, take row max ONCE as the fixed reference
            const float sth = srate * (float)thr;
            float pv[16];
            float mx = -3e38f;
            #pragma unroll
            for (int t = 0; t < 4; ++t)
                #pragma unroll
                for (int r = 0; r < 4; ++r) {
                    const int jj = t*16 + lg*4 + r;
                    float v = fmaf(sAcc[t][r], sscale, joff[t*4+r] - sth);
                    if (jj > thr) v = -3e38f;
                    pv[t*4+r] = v;
                    mx = fmaxf(mx, v);
                }
            mx = fmaxf(mx, __shfl_xor(mx, 16, 64));
            mx = fmaxf(mx, __shfl_xor(mx, 32, 64));
            mrow = mx;
            #pragma unroll
            for (int i = 0; i < 16; ++i) {
                e[i] = __builtin_amdgcn_exp2f(pv[i] - mx);
                den += e[i];
            }
        } else {
            // fast path: no mask, no max tracking; fold m into the constant
            const float c0m = fmaf(srate, (float)(j0 - ig), -mrow);
            #pragma unroll
            for (int t = 0; t < 4; ++t)
                #pragma unroll
                for (int r = 0; r < 4; ++r) {
                    const float v = fmaf(sAcc[t][r], sscale, c0m + joff[t*4+r]);
                    const float p = __builtin_amdgcn_exp2f(v);
                    e[t*4+r] = p;
                    den += p;
                }
        }

        // pack P (bf16) into wave-private LDS rows
        #pragma unroll
        for (int t = 0; t < 4; ++t) {
            u16x4 pk = { f2bf(e[t*4]), f2bf(e[t*4+1]), f2bf(e[t*4+2]), f2bf(e[t*4+3]) };
            *(u16x4*)&PsW[swz(l15, t*16 + lg*4)] = pk;
        }

        // PV
        __builtin_amdgcn_s_setprio(1);
        #pragma unroll
        for (int kf = 0; kf < 2; ++kf) {
            bf16x8 pa = *(const bf16x8*)&PsW[ridx(l15, kf*4 + lg)];
            #pragma unroll
            for (int n = 0; n < 4; ++n) {
                bf16x8 vf = *(const bf16x8*)&Vt[cur][ridx(n*16 + l15, kf*4 + lg)];
                oAcc[n] = mfma16(pa, vf, oAcc[n]);
            }
        }
        __builtin_amdgcn_s_setprio(0);
        __syncthreads();                       // drain next-tile loads + reads
        cur ^= 1;
    }

    // single end-of-loop reduction + normalize + store
    den += __shfl_xor(den, 16, 64);
    den += __shfl_xor(den, 32, 64);
    const float inv = 1.f / den;
    float ivr[4];
    #pragma unroll
    for (int r = 0; r < 4; ++r) ivr[r] = __shfl(inv, lg*4 + r, 64);
    #pragma unroll
    for (int r = 0; r < 4; ++r) {
        const int row = i0 + wid*16 + lg*4 + r;
        #pragma unroll
        for (int n = 0; n < 4; ++n)
            g_y[(size_t)(bb*T_ + row)*C_ + h*D_ + n*16 + l15] = f2bf(oAcc[n][r] * ivr[r]);
    }
}

// ---------------------------------------------------------------------------
// Kernel 3: out = y @ W_proj + b_proj (same dbuf structure, fp32 out)
// ---------------------------------------------------------------------------
__global__ __launch_bounds__(256) void k_proj(const float* __restrict__ bias,
                                              float* __restrict__ out)
{
    __shared__ u16 As[2][128*64];
    __shared__ u16 Bs[2][128*64];

    const int tid  = threadIdx.x;
    const int lane = tid & 63;
    const int wid  = tid >> 6;
    const int l15  = lane & 15;
    const int lg   = lane >> 4;
    const int wm = wid >> 1, wn = wid & 1;
    const int m0 = blockIdx.x * 128;
    const int n0 = blockIdx.y * 128;

    const int srow8 = lane >> 3;
    const int schk  = (lane & 7) ^ srow8;

    f32x4 acc[4][4];
    #pragma unroll
    for (int i = 0; i < 4; ++i)
        #pragma unroll
        for (int j = 0; j < 4; ++j) acc[i][j] = (f32x4){0.f,0.f,0.f,0.f};

    const u16* ya = &g_y  [(size_t)(m0 + wid*32 + srow8)*C_ + (schk<<3)];
    const u16* wb = &g_wpt[(size_t)(n0 + wid*32 + srow8)*C_ + (schk<<3)];

    #pragma unroll
    for (int i = 0; i < 4; ++i) {
        const int r = wid*32 + i*8;
        gl16(ya + (size_t)i*8*C_, &As[0][r*64]);
        gl16(wb + (size_t)i*8*C_, &Bs[0][r*64]);
    }
    __syncthreads();

    int cur = 0;
    for (int k = 0; k < 12; ++k) {
        if (k < 11) {
            const int ko = (k+1)*64;
            #pragma unroll
            for (int i = 0; i < 4; ++i) {
                const int r = wid*32 + i*8;
                gl16(ya + (size_t)i*8*C_ + ko, &As[cur^1][r*64]);
                gl16(wb + (size_t)i*8*C_ + ko, &Bs[cur^1][r*64]);
            }
        }
        __builtin_amdgcn_s_setprio(1);
        #pragma unroll
        for (int kf = 0; kf < 2; ++kf) {
            bf16x8 bfr[4];
            #pragma unroll
            for (int nt = 0; nt < 4; ++nt) {
                const int rw = wn*64 + nt*16 + l15;
                bfr[nt] = *(const bf16x8*)&Bs[cur][ridx(rw, kf*4 + lg)];
            }
            #pragma unroll
            for (int mt = 0; mt < 4; ++mt) {
                const int rw = wm*64 + mt*16 + l15;
                bf16x8 afr = *(const bf16x8*)&As[cur][ridx(rw, kf*4 + lg)];
                #pragma unroll
                for (int nt = 0; nt < 4; ++nt)
                    acc[mt][nt] = mfma16(afr, bfr[nt], acc[mt][nt]);
            }
        }
        __builtin_amdgcn_s_setprio(0);
        __syncthreads();
        cur ^= 1;
    }

    float bv4[4];
    #pragma unroll
    for (int nt = 0; nt < 4; ++nt) bv4[nt] = bias[n0 + wn*64 + nt*16 + l15];
    #pragma unroll
    for (int mt = 0; mt < 4; ++mt)
        #pragma unroll
        for (int r = 0; r < 4; ++r) {
            const int m = m0 + wm*64 + mt*16 + lg*4 + r;
            #pragma unroll
            for (int nt = 0; nt < 4; ++nt)
                out[(size_t)m*C_ + n0 + wn*64 + nt*16 + l15] = acc[mt][nt][r] + bv4[nt];
        }
}

extern "C" void kernel_launch(void* const* d_in, const int* in_sizes, int n_in,
                              void* d_out, int out_size, void* d_ws, size_t ws_size,
                              hipStream_t stream) {
    (void)in_sizes; (void)n_in; (void)d_ws; (void)ws_size; (void)out_size;
    const float* x      = (const float*)d_in[0];
    const float* W_attn = (const float*)d_in[1];
    const float* b_attn = (const float*)d_in[2];
    const float* W_proj = (const float*)d_in[3];
    const float* b_proj = (const float*)d_in[4];
    const float* rates  = (const float*)d_in[5];

    hipLaunchKernelGGL(k_prep_x, dim3(M_*C_/8/256), dim3(256), 0, stream, x);
    hipLaunchKernelGGL(k_prep_w, dim3(QKV_N/64 + C_/64, C_/64), dim3(256), 0, stream, W_attn, W_proj);
    hipLaunchKernelGGL(k_qkv,  dim3(M_/128, QKV_N/128), dim3(256), 0, stream, b_attn);
    hipLaunchKernelGGL(k_attn, dim3(1536),              dim3(256), 0, stream, rates);
    hipLaunchKernelGGL(k_proj, dim3(M_/128, C_/128),    dim3(256), 0, stream, b_proj, (float*)d_out);
}